// Round 8
// baseline (256.216 us; speedup 1.0000x reference)
//
#include <hip/hip_runtime.h>
#include <hip/hip_bf16.h>

#define BDIM 16384
#define CDIM 128
#define FDIM 5000
#define EDIM 20000
#define ELLW 16
#define MAXOVF 20000
#define NT4  10       // n-tile QUADS: 40 n-tiles / 4

typedef __attribute__((ext_vector_type(8))) short short8;
typedef __attribute__((ext_vector_type(4))) float f32x4;
typedef __attribute__((ext_vector_type(2))) float f32x2;
typedef __attribute__((ext_vector_type(2))) int i32x2;
typedef __attribute__((ext_vector_type(4))) int i32x4;
typedef __attribute__((ext_vector_type(8))) unsigned short upk8;
typedef __attribute__((ext_vector_type(4))) unsigned short upk4;
typedef __attribute__((ext_vector_type(2))) unsigned int u32x2;

__device__ __forceinline__ unsigned short f2bf(float f) {
    unsigned int u = __builtin_bit_cast(unsigned int, f);
    u = (u + 0x7fffu + ((u >> 16) & 1u)) >> 16;   // RNE
    return (unsigned short)u;
}
__device__ __forceinline__ float bf2f(unsigned short s) {
    unsigned int u = ((unsigned int)s) << 16;
    return __builtin_bit_cast(float, u);
}
__device__ __forceinline__ upk8 umax8(upk8 a, upk8 b) {
#if __has_builtin(__builtin_elementwise_max)
    return __builtin_elementwise_max(a, b);   // 4x v_pk_max_u16
#else
    upk8 r;
    #pragma unroll
    for (int j = 0; j < 8; ++j) r[j] = a[j] > b[j] ? a[j] : b[j];
    return r;
#endif
}
// single v_rcp_f32. VERIFIED WIN round 2: 178.96 -> 159.24 us.
__device__ __forceinline__ float fast_rcp(float x) {
#if __has_builtin(__builtin_amdgcn_rcpf)
    return __builtin_amdgcn_rcpf(x);
#else
    return 1.0f / x;
#endif
}
// order-preserving u16 key of a bf16 pattern h (per 16-bit half, packed u32).
// VERIFIED WIN round 4: 159.24 -> 153.83 us, absmax 0.0059 -> 0.0039.
__device__ __forceinline__ unsigned int key2(unsigned int h) {
    unsigned int t = (h >> 15) & 0x00010001u;
    return h ^ (t * 0x7FFFu + 0x80008000u);
}
// inverse: k -> bf16 bits
__device__ __forceinline__ unsigned short unkey(unsigned short k) {
    unsigned int s = (k >> 15) & 1u;
    return (unsigned short)(k ^ (0x8000u + ((s ^ 1u) * 0x7FFFu)));
}
__device__ __forceinline__ float sigk(unsigned short k) {
    return fast_rcp(1.0f + __expf(-bf2f(unkey(k))));
}
// async global->LDS, 16B per lane; LDS dest = firstlane base + lane*16
__device__ __forceinline__ void gll16(const unsigned short* g, unsigned short* l) {
    __builtin_amdgcn_global_load_lds(
        (const __attribute__((address_space(1))) void*)g,
        (__attribute__((address_space(3))) void*)l, 16, 0, 0);
}

// ---------------------------------------------------------------------------
// prep1: blocks [0,1024): x f32 -> bf16 (2048 elems/block)
//        blocks [1024,1181): W[k][f] -> Wt[f][k] bf16, LDS-tiled
//        blocks [1181,1201): ELL init (all 16 slots = self), cur=1, ovf=0
// ---------------------------------------------------------------------------
__global__ __launch_bounds__(256) void prep1_kernel(
    const float* __restrict__ x, const float* __restrict__ W,
    unsigned short* __restrict__ xb, unsigned short* __restrict__ wt,
    unsigned short* __restrict__ ell, int* __restrict__ cur,
    int* __restrict__ ovf_cnt)
{
    __shared__ float lt[128][33];
    int bid = blockIdx.x, tid = threadIdx.x;
    if (bid < 1024) {
        size_t base = (size_t)bid * 2048 + (size_t)tid * 8;
        const f32x4* p = (const f32x4*)(x + base);
        f32x4 v0 = p[0], v1 = p[1];
        short8 o;
        o[0] = (short)f2bf(v0[0]); o[1] = (short)f2bf(v0[1]);
        o[2] = (short)f2bf(v0[2]); o[3] = (short)f2bf(v0[3]);
        o[4] = (short)f2bf(v1[0]); o[5] = (short)f2bf(v1[1]);
        o[6] = (short)f2bf(v1[2]); o[7] = (short)f2bf(v1[3]);
        *(short8*)(xb + base) = o;
    } else if (bid < 1181) {
        int f0 = (bid - 1024) * 32;
        int f_l = tid & 31, k0 = (tid >> 5) * 16;
        #pragma unroll
        for (int i = 0; i < 16; ++i) {
            int f = f0 + f_l;
            lt[k0 + i][f_l] = (f < FDIM) ? W[(size_t)(k0 + i) * FDIM + f] : 0.f;
        }
        __syncthreads();
        int f_l2 = tid >> 3, ks = (tid & 7) * 16;
        int f = f0 + f_l2;
        if (f < FDIM) {
            short8 o0, o1;
            #pragma unroll
            for (int j = 0; j < 8; ++j) o0[j] = (short)f2bf(lt[ks + j][f_l2]);
            #pragma unroll
            for (int j = 0; j < 8; ++j) o1[j] = (short)f2bf(lt[ks + 8 + j][f_l2]);
            *(short8*)(wt + (size_t)f * 128 + ks)     = o0;
            *(short8*)(wt + (size_t)f * 128 + ks + 8) = o1;
        }
    } else {
        int p = (bid - 1181) * 256 + tid;
        if (p < FDIM) {
            upk8 s;
            #pragma unroll
            for (int j = 0; j < 8; ++j) s[j] = (unsigned short)p;
            *(upk8*)(ell + (size_t)p * ELLW)     = s;
            *(upk8*)(ell + (size_t)p * ELLW + 8) = s;
            cur[p] = 1;
        }
        if (p == FDIM) *ovf_cnt = 0;
    }
}

// ---------------------------------------------------------------------------
// prep2: scatter children into ELL slots 1.. (order irrelevant: max).
// ---------------------------------------------------------------------------
__global__ __launch_bounds__(256) void prep2_kernel(
    const int* __restrict__ epar, const int* __restrict__ echild,
    int* __restrict__ cur, unsigned short* __restrict__ ell,
    int* __restrict__ ovf_cnt, int* __restrict__ ovf_pairs)
{
    int i = blockIdx.x * 256 + threadIdx.x;
    if (i < EDIM) {
        int p = epar[i], c = echild[i];
        if (p != c) {
            int pos = atomicAdd(&cur[p], 1);
            if (pos < ELLW) {
                ell[(size_t)p * ELLW + pos] = (unsigned short)c;
            } else {
                int j = atomicAdd(ovf_cnt, 1);
                if (j < MAXOVF) { ovf_pairs[2 * j] = p; ovf_pairs[2 * j + 1] = c; }
            }
        }
    }
}

// ---------------------------------------------------------------------------
// gemm8k: EXACT r4 verified version (153.83 us pipeline; warm gemm ~37 us
// measured r6).
// ---------------------------------------------------------------------------
__global__ __launch_bounds__(512, 4) void gemm8k_kernel(
    const unsigned short* __restrict__ xb,   // [BDIM][128] bf16
    const unsigned short* __restrict__ wt,   // [FDIM][128] bf16
    const float* __restrict__ bias,
    unsigned short* __restrict__ probs16)    // [BDIM/8][FDIM][8] u16 keys
{
    __shared__ unsigned short lA[128 * 128];
    __shared__ unsigned short lB[128 * 128];

    int bid0 = blockIdx.x;
    int bid  = (bid0 & 7) * (128 * NT4 / 8) + (bid0 >> 3);   // XCD swizzle
    int bm = bid / NT4, bq = bid % NT4;
    int tid = threadIdx.x;
    int lane = tid & 63, w = tid >> 6;       // 8 waves
    int wm = w >> 2, wn = w & 3;
    int g = lane >> 4, lr = lane & 15;
    int lrow = lane >> 4;                    // row within 4-row chunk
    int lcol = (lane & 15) << 4;             // byte col

    auto stageA = [&]() {
        #pragma unroll
        for (int it = 0; it < 4; ++it) {
            int ci = w * 4 + it;             // chunk 0..31
            int row = ci * 4 + lrow;
            int sw = lcol ^ ((row & 7) << 4);
            gll16(xb + ((size_t)(bm * 128 + row) << 7) + (sw >> 1),
                  lA + ci * 512);
        }
    };
    auto stageB = [&](int bn) {
        #pragma unroll
        for (int it = 0; it < 4; ++it) {
            int ci = w * 4 + it;
            int row = ci * 4 + lrow;
            int sw = lcol ^ ((row & 7) << 4);
            gll16(wt + ((size_t)(bn * 128 + row) << 7) + (sw >> 1),
                  lB + ci * 512);
        }
    };
    auto compute = [&](f32x4 (&acc)[4][2]) {
        #pragma unroll
        for (int ks = 0; ks < 4; ++ks) {
            int cbk = ks * 64 + g * 16;
            short8 af[4], bf[2];
            #pragma unroll
            for (int mi = 0; mi < 4; ++mi) {
                int row = wm * 64 + mi * 16 + lr;
                af[mi] = *(const short8*)((const char*)lA + row * 256 + (cbk ^ ((row & 7) << 4)));
            }
            #pragma unroll
            for (int nj = 0; nj < 2; ++nj) {
                int row = wn * 32 + nj * 16 + lr;
                bf[nj] = *(const short8*)((const char*)lB + row * 256 + (cbk ^ ((row & 7) << 4)));
            }
            #pragma unroll
            for (int mi = 0; mi < 4; ++mi)
                #pragma unroll
                for (int nj = 0; nj < 2; ++nj)
                    acc[mi][nj] = __builtin_amdgcn_mfma_f32_16x16x32_bf16(
                        af[mi], bf[nj], acc[mi][nj], 0, 0, 0);
        }
    };
    auto epilogue = [&](int bn, f32x4 (&acc)[4][2]) {
        #pragma unroll
        for (int nj = 0; nj < 2; ++nj) {
            int f = bn * 128 + wn * 32 + nj * 16 + lr;
            bool ok = (f < FDIM);
            float bb = ok ? bias[f] : 0.f;
            #pragma unroll
            for (int mi = 0; mi < 4; ++mi) {
                float z0 = acc[mi][nj][0] + bb;
                float z1 = acc[mi][nj][1] + bb;
                float z2 = acc[mi][nj][2] + bb;
                float z3 = acc[mi][nj][3] + bb;
                unsigned int h01, h23;   // packed bf16 (low = first operand)
                asm("v_cvt_pk_bf16_f32 %0, %1, %2" : "=v"(h01) : "v"(z0), "v"(z1));
                asm("v_cvt_pk_bf16_f32 %0, %1, %2" : "=v"(h23) : "v"(z2), "v"(z3));
                u32x2 st;
                st[0] = key2(h01);
                st[1] = key2(h23);
                if (ok) {
                    int slab = bm * 16 + wm * 8 + mi * 2 + (g >> 1);
                    *(u32x2*)(probs16 + ((size_t)slab * FDIM + f) * 8 + (g & 1) * 4) = st;
                }
            }
        }
    };

    stageA();
    stageB(bq * 4);
    __syncthreads();                     // drains vmcnt -> tiles resident

    f32x4 zero = {0.f, 0.f, 0.f, 0.f};
    for (int t = 0; t < 4; ++t) {
        f32x4 acc[4][2];
        #pragma unroll
        for (int mi = 0; mi < 4; ++mi) { acc[mi][0] = zero; acc[mi][1] = zero; }
        compute(acc);
        if (t < 3) {
            __syncthreads();             // all waves done reading lB(t)
            stageB(bq * 4 + t + 1);      // async B(t+1), hides under epilogue
            epilogue(bq * 4 + t, acc);
            __syncthreads();             // drains vmcnt -> lB(t+1) ready
        } else {
            epilogue(bq * 4 + t, acc);
        }
    }
}

// ---------------------------------------------------------------------------
// segmax14: NO LDS TABLE. A slab's gathers touch only its own 80 KB slice
// of probs16 (L2/L3-resident) -> gather DIRECTLY from global. Removes the
// staging pass, the barrier, and the block-lockstep phase structure that
// idled HBM writes (theory r7 post-mortem: 4 rounds of stage/gather/drain
// ~= 109 us). Pure stream: ell/cur load -> L2 gathers -> max -> sigmoid ->
// nontemporal store. Main path: 4 ADJACENT parents/thread (4t..4t+3) ->
// i32x4 cur, contiguous ell rows, f32x4 out stores. Tail: pairs at
// 4096+2t for tid<452. Math identical to segmax12/13.
// ---------------------------------------------------------------------------
__global__ __launch_bounds__(1024, 8) void segmax14_kernel(
    const unsigned short* __restrict__ probs16,
    const int* __restrict__ cur, const unsigned short* __restrict__ ell,
    const int* __restrict__ ovf_cnt, const int* __restrict__ ovf_pairs,
    float* __restrict__ out)
{
    int slab = blockIdx.x;
    int b0 = slab * 8;
    int tid = threadIdx.x;
    const unsigned short* src = probs16 + (size_t)slab * FDIM * 8;

    int novf = *ovf_cnt; if (novf > MAXOVF) novf = MAXOVF;

    // ---- main: 4 adjacent parents 4t..4t+3, cross-parent ILP ----
    {
        int p0 = tid * 4;                    // < 4096 always
        i32x4 dg4 = *(const i32x4*)(cur + p0);
        upk8 er[4];
        #pragma unroll
        for (int j = 0; j < 4; ++j)
            er[j] = *(const upk8*)(ell + (size_t)(p0 + j) * ELLW);  // slots 0-7

        upk8 m[4];
        #pragma unroll
        for (int j = 0; j < 4; ++j)
            m[j] = *(const upk8*)(src + (size_t)er[j][0] * 8);
        #pragma unroll
        for (int s = 1; s < 4; ++s)
            #pragma unroll
            for (int j = 0; j < 4; ++j)
                m[j] = umax8(m[j], *(const upk8*)(src + (size_t)er[j][s] * 8));

        #pragma unroll
        for (int j = 0; j < 4; ++j) {
            if (dg4[j] > 4) {                // slots 4-7 already in er[j]
                m[j] = umax8(m[j], *(const upk8*)(src + (size_t)er[j][4] * 8));
                m[j] = umax8(m[j], *(const upk8*)(src + (size_t)er[j][5] * 8));
                m[j] = umax8(m[j], *(const upk8*)(src + (size_t)er[j][6] * 8));
                m[j] = umax8(m[j], *(const upk8*)(src + (size_t)er[j][7] * 8));
            }
        }
        #pragma unroll
        for (int j = 0; j < 4; ++j) {
            int pj = p0 + j;
            if (dg4[j] > 8) {
                upk8 e2 = *(const upk8*)(ell + (size_t)pj * ELLW + 8);
                #pragma unroll
                for (int k = 0; k < 8; ++k)
                    m[j] = umax8(m[j], *(const upk8*)(src + (size_t)e2[k] * 8));
            }
            if (dg4[j] > ELLW) {
                for (int i = 0; i < novf; ++i)
                    if (ovf_pairs[2 * i] == pj)
                        m[j] = umax8(m[j], *(const upk8*)(src + (size_t)ovf_pairs[2 * i + 1] * 8));
            }
        }

        size_t o = (size_t)b0 * FDIM + p0;
        #pragma unroll
        for (int r = 0; r < 8; ++r) {
            f32x4 v4;
            #pragma unroll
            for (int j = 0; j < 4; ++j)
                v4[j] = sigk(m[j][r]);
            __builtin_nontemporal_store(v4, (f32x4*)(out + o + (size_t)r * FDIM));
        }
    }

    // ---- tail: pair (4096+2t, 4097+2t), only for tid < 452 ----
    int pt = 4096 + tid * 2;
    if (pt < FDIM) {
        int p1 = pt + 1;
        i32x2 dg = *(const i32x2*)(cur + pt);
        upk8 ea = *(const upk8*)(ell + (size_t)pt * ELLW);   // slots 0-7
        upk8 eb = *(const upk8*)(ell + (size_t)p1 * ELLW);
        upk8 ma = *(const upk8*)(src + (size_t)ea[0] * 8);
        upk8 mb = *(const upk8*)(src + (size_t)eb[0] * 8);
        ma = umax8(ma, *(const upk8*)(src + (size_t)ea[1] * 8));
        mb = umax8(mb, *(const upk8*)(src + (size_t)eb[1] * 8));
        ma = umax8(ma, *(const upk8*)(src + (size_t)ea[2] * 8));
        mb = umax8(mb, *(const upk8*)(src + (size_t)eb[2] * 8));
        ma = umax8(ma, *(const upk8*)(src + (size_t)ea[3] * 8));
        mb = umax8(mb, *(const upk8*)(src + (size_t)eb[3] * 8));
        if (dg[0] > 4) {
            ma = umax8(ma, *(const upk8*)(src + (size_t)ea[4] * 8));
            ma = umax8(ma, *(const upk8*)(src + (size_t)ea[5] * 8));
            ma = umax8(ma, *(const upk8*)(src + (size_t)ea[6] * 8));
            ma = umax8(ma, *(const upk8*)(src + (size_t)ea[7] * 8));
        }
        if (dg[1] > 4) {
            mb = umax8(mb, *(const upk8*)(src + (size_t)eb[4] * 8));
            mb = umax8(mb, *(const upk8*)(src + (size_t)eb[5] * 8));
            mb = umax8(mb, *(const upk8*)(src + (size_t)eb[6] * 8));
            mb = umax8(mb, *(const upk8*)(src + (size_t)eb[7] * 8));
        }
        if (dg[0] > 8) {
            upk8 e = *(const upk8*)(ell + (size_t)pt * ELLW + 8);
            #pragma unroll
            for (int k = 0; k < 8; ++k)
                ma = umax8(ma, *(const upk8*)(src + (size_t)e[k] * 8));
        }
        if (dg[1] > 8) {
            upk8 e = *(const upk8*)(ell + (size_t)p1 * ELLW + 8);
            #pragma unroll
            for (int k = 0; k < 8; ++k)
                mb = umax8(mb, *(const upk8*)(src + (size_t)e[k] * 8));
        }
        if (dg[0] > ELLW) {
            for (int i = 0; i < novf; ++i)
                if (ovf_pairs[2 * i] == pt)
                    ma = umax8(ma, *(const upk8*)(src + (size_t)ovf_pairs[2 * i + 1] * 8));
        }
        if (dg[1] > ELLW) {
            for (int i = 0; i < novf; ++i)
                if (ovf_pairs[2 * i] == p1)
                    mb = umax8(mb, *(const upk8*)(src + (size_t)ovf_pairs[2 * i + 1] * 8));
        }
        size_t o = (size_t)b0 * FDIM + pt;
        #pragma unroll
        for (int r = 0; r < 8; ++r) {
            f32x2 v2;
            v2[0] = sigk(ma[r]);
            v2[1] = sigk(mb[r]);
            __builtin_nontemporal_store(v2, (f32x2*)(out + o + (size_t)r * FDIM));
        }
    }
}

// ---------------------------------------------------------------------------
extern "C" void kernel_launch(void* const* d_in, const int* in_sizes, int n_in,
                              void* d_out, int out_size, void* d_ws, size_t ws_size,
                              hipStream_t stream)
{
    const float* x     = (const float*)d_in[0];
    const float* W     = (const float*)d_in[1];
    const float* bias  = (const float*)d_in[2];
    const int*   epar  = (const int*)d_in[3];
    const int*   echild= (const int*)d_in[4];
    float* out = (float*)d_out;

    char* ws = (char*)d_ws;
    size_t off = 0;
    auto alloc = [&](size_t bytes) { size_t o = off; off = (off + bytes + 255) & ~(size_t)255; return o; };
    size_t o_probs  = alloc((size_t)BDIM * FDIM * 2);    // u16 keys
    size_t o_xb     = alloc((size_t)BDIM * CDIM * 2);
    size_t o_wt     = alloc((size_t)FDIM * CDIM * 2);
    size_t o_ell    = alloc((size_t)FDIM * ELLW * 2);
    size_t o_cur    = alloc((size_t)FDIM * 4);
    size_t o_ovfc   = alloc(4);
    size_t o_ovfp   = alloc((size_t)MAXOVF * 8);
    (void)ws_size; (void)in_sizes; (void)n_in; (void)out_size;

    unsigned short* probs16 = (unsigned short*)(ws + o_probs);
    unsigned short* xb      = (unsigned short*)(ws + o_xb);
    unsigned short* wt      = (unsigned short*)(ws + o_wt);
    unsigned short* ell     = (unsigned short*)(ws + o_ell);
    int* cur      = (int*)(ws + o_cur);
    int* ovf_cnt  = (int*)(ws + o_ovfc);
    int* ovf_pairs= (int*)(ws + o_ovfp);

    prep1_kernel<<<1201, 256, 0, stream>>>(x, W, xb, wt, ell, cur, ovf_cnt);
    prep2_kernel<<<79, 256, 0, stream>>>(epar, echild, cur, ell, ovf_cnt, ovf_pairs);
    gemm8k_kernel<<<128 * NT4, 512, 0, stream>>>(xb, wt, bias, probs16);
    segmax14_kernel<<<BDIM / 8, 1024, 0, stream>>>(probs16, cur, ell,
                                                   ovf_cnt, ovf_pairs, out);
}

// Round 9
// 158.853 us; speedup vs baseline: 1.6129x; 1.6129x over previous
//
#include <hip/hip_runtime.h>
#include <hip/hip_bf16.h>

#define BDIM 16384
#define CDIM 128
#define FDIM 5000
#define EDIM 20000
#define ELLW 16
#define MAXOVF 20000
#define NT4  10       // n-tile QUADS: 40 n-tiles / 4

typedef __attribute__((ext_vector_type(8))) short short8;
typedef __attribute__((ext_vector_type(4))) float f32x4;
typedef __attribute__((ext_vector_type(2))) float f32x2;
typedef __attribute__((ext_vector_type(2))) int i32x2;
typedef __attribute__((ext_vector_type(8))) unsigned short upk8;
typedef __attribute__((ext_vector_type(4))) unsigned short upk4;
typedef __attribute__((ext_vector_type(2))) unsigned int u32x2;

__device__ __forceinline__ unsigned short f2bf(float f) {
    unsigned int u = __builtin_bit_cast(unsigned int, f);
    u = (u + 0x7fffu + ((u >> 16) & 1u)) >> 16;   // RNE
    return (unsigned short)u;
}
__device__ __forceinline__ float bf2f(unsigned short s) {
    unsigned int u = ((unsigned int)s) << 16;
    return __builtin_bit_cast(float, u);
}
__device__ __forceinline__ upk8 umax8(upk8 a, upk8 b) {
#if __has_builtin(__builtin_elementwise_max)
    return __builtin_elementwise_max(a, b);   // 4x v_pk_max_u16
#else
    upk8 r;
    #pragma unroll
    for (int j = 0; j < 8; ++j) r[j] = a[j] > b[j] ? a[j] : b[j];
    return r;
#endif
}
// single v_rcp_f32. VERIFIED WIN round 2: 178.96 -> 159.24 us.
__device__ __forceinline__ float fast_rcp(float x) {
#if __has_builtin(__builtin_amdgcn_rcpf)
    return __builtin_amdgcn_rcpf(x);
#else
    return 1.0f / x;
#endif
}
// order-preserving u16 key of a bf16 pattern h (per 16-bit half, packed u32).
// VERIFIED WIN round 4: 159.24 -> 153.83 us, absmax 0.0059 -> 0.0039.
__device__ __forceinline__ unsigned int key2(unsigned int h) {
    unsigned int t = (h >> 15) & 0x00010001u;
    return h ^ (t * 0x7FFFu + 0x80008000u);
}
// inverse: k -> bf16 bits
__device__ __forceinline__ unsigned short unkey(unsigned short k) {
    unsigned int s = (k >> 15) & 1u;
    return (unsigned short)(k ^ (0x8000u + ((s ^ 1u) * 0x7FFFu)));
}
__device__ __forceinline__ float sigk(unsigned short k) {
    return fast_rcp(1.0f + __expf(-bf2f(unkey(k))));
}
// async global->LDS, 16B per lane; LDS dest = firstlane base + lane*16
__device__ __forceinline__ void gll16(const unsigned short* g, unsigned short* l) {
    __builtin_amdgcn_global_load_lds(
        (const __attribute__((address_space(1))) void*)g,
        (__attribute__((address_space(3))) void*)l, 16, 0, 0);
}

// ---------------------------------------------------------------------------
// prep1: blocks [0,1024): x f32 -> bf16 (2048 elems/block)
//        blocks [1024,1181): W[k][f] -> Wt[f][k] bf16, LDS-tiled
//        blocks [1181,1201): ELL init (all 16 slots = self), cur=1, ovf=0
// ---------------------------------------------------------------------------
__global__ __launch_bounds__(256) void prep1_kernel(
    const float* __restrict__ x, const float* __restrict__ W,
    unsigned short* __restrict__ xb, unsigned short* __restrict__ wt,
    unsigned short* __restrict__ ell, int* __restrict__ cur,
    int* __restrict__ ovf_cnt)
{
    __shared__ float lt[128][33];
    int bid = blockIdx.x, tid = threadIdx.x;
    if (bid < 1024) {
        size_t base = (size_t)bid * 2048 + (size_t)tid * 8;
        const f32x4* p = (const f32x4*)(x + base);
        f32x4 v0 = p[0], v1 = p[1];
        short8 o;
        o[0] = (short)f2bf(v0[0]); o[1] = (short)f2bf(v0[1]);
        o[2] = (short)f2bf(v0[2]); o[3] = (short)f2bf(v0[3]);
        o[4] = (short)f2bf(v1[0]); o[5] = (short)f2bf(v1[1]);
        o[6] = (short)f2bf(v1[2]); o[7] = (short)f2bf(v1[3]);
        *(short8*)(xb + base) = o;
    } else if (bid < 1181) {
        int f0 = (bid - 1024) * 32;
        int f_l = tid & 31, k0 = (tid >> 5) * 16;
        #pragma unroll
        for (int i = 0; i < 16; ++i) {
            int f = f0 + f_l;
            lt[k0 + i][f_l] = (f < FDIM) ? W[(size_t)(k0 + i) * FDIM + f] : 0.f;
        }
        __syncthreads();
        int f_l2 = tid >> 3, ks = (tid & 7) * 16;
        int f = f0 + f_l2;
        if (f < FDIM) {
            short8 o0, o1;
            #pragma unroll
            for (int j = 0; j < 8; ++j) o0[j] = (short)f2bf(lt[ks + j][f_l2]);
            #pragma unroll
            for (int j = 0; j < 8; ++j) o1[j] = (short)f2bf(lt[ks + 8 + j][f_l2]);
            *(short8*)(wt + (size_t)f * 128 + ks)     = o0;
            *(short8*)(wt + (size_t)f * 128 + ks + 8) = o1;
        }
    } else {
        int p = (bid - 1181) * 256 + tid;
        if (p < FDIM) {
            upk8 s;
            #pragma unroll
            for (int j = 0; j < 8; ++j) s[j] = (unsigned short)p;
            *(upk8*)(ell + (size_t)p * ELLW)     = s;
            *(upk8*)(ell + (size_t)p * ELLW + 8) = s;
            cur[p] = 1;
        }
        if (p == FDIM) *ovf_cnt = 0;
    }
}

// ---------------------------------------------------------------------------
// prep2: scatter children into ELL slots 1.. (order irrelevant: max).
// ---------------------------------------------------------------------------
__global__ __launch_bounds__(256) void prep2_kernel(
    const int* __restrict__ epar, const int* __restrict__ echild,
    int* __restrict__ cur, unsigned short* __restrict__ ell,
    int* __restrict__ ovf_cnt, int* __restrict__ ovf_pairs)
{
    int i = blockIdx.x * 256 + threadIdx.x;
    if (i < EDIM) {
        int p = epar[i], c = echild[i];
        if (p != c) {
            int pos = atomicAdd(&cur[p], 1);
            if (pos < ELLW) {
                ell[(size_t)p * ELLW + pos] = (unsigned short)c;
            } else {
                int j = atomicAdd(ovf_cnt, 1);
                if (j < MAXOVF) { ovf_pairs[2 * j] = p; ovf_pairs[2 * j + 1] = c; }
            }
        }
    }
}

// ---------------------------------------------------------------------------
// gemm8k: EXACT r4 verified version (153.83 us pipeline; warm gemm ~37 us
// measured r6).
// ---------------------------------------------------------------------------
__global__ __launch_bounds__(512, 4) void gemm8k_kernel(
    const unsigned short* __restrict__ xb,   // [BDIM][128] bf16
    const unsigned short* __restrict__ wt,   // [FDIM][128] bf16
    const float* __restrict__ bias,
    unsigned short* __restrict__ probs16)    // [BDIM/8][FDIM][8] u16 keys
{
    __shared__ unsigned short lA[128 * 128];
    __shared__ unsigned short lB[128 * 128];

    int bid0 = blockIdx.x;
    int bid  = (bid0 & 7) * (128 * NT4 / 8) + (bid0 >> 3);   // XCD swizzle
    int bm = bid / NT4, bq = bid % NT4;
    int tid = threadIdx.x;
    int lane = tid & 63, w = tid >> 6;       // 8 waves
    int wm = w >> 2, wn = w & 3;
    int g = lane >> 4, lr = lane & 15;
    int lrow = lane >> 4;                    // row within 4-row chunk
    int lcol = (lane & 15) << 4;             // byte col

    auto stageA = [&]() {
        #pragma unroll
        for (int it = 0; it < 4; ++it) {
            int ci = w * 4 + it;             // chunk 0..31
            int row = ci * 4 + lrow;
            int sw = lcol ^ ((row & 7) << 4);
            gll16(xb + ((size_t)(bm * 128 + row) << 7) + (sw >> 1),
                  lA + ci * 512);
        }
    };
    auto stageB = [&](int bn) {
        #pragma unroll
        for (int it = 0; it < 4; ++it) {
            int ci = w * 4 + it;
            int row = ci * 4 + lrow;
            int sw = lcol ^ ((row & 7) << 4);
            gll16(wt + ((size_t)(bn * 128 + row) << 7) + (sw >> 1),
                  lB + ci * 512);
        }
    };
    auto compute = [&](f32x4 (&acc)[4][2]) {
        #pragma unroll
        for (int ks = 0; ks < 4; ++ks) {
            int cbk = ks * 64 + g * 16;
            short8 af[4], bf[2];
            #pragma unroll
            for (int mi = 0; mi < 4; ++mi) {
                int row = wm * 64 + mi * 16 + lr;
                af[mi] = *(const short8*)((const char*)lA + row * 256 + (cbk ^ ((row & 7) << 4)));
            }
            #pragma unroll
            for (int nj = 0; nj < 2; ++nj) {
                int row = wn * 32 + nj * 16 + lr;
                bf[nj] = *(const short8*)((const char*)lB + row * 256 + (cbk ^ ((row & 7) << 4)));
            }
            #pragma unroll
            for (int mi = 0; mi < 4; ++mi)
                #pragma unroll
                for (int nj = 0; nj < 2; ++nj)
                    acc[mi][nj] = __builtin_amdgcn_mfma_f32_16x16x32_bf16(
                        af[mi], bf[nj], acc[mi][nj], 0, 0, 0);
        }
    };
    auto epilogue = [&](int bn, f32x4 (&acc)[4][2]) {
        #pragma unroll
        for (int nj = 0; nj < 2; ++nj) {
            int f = bn * 128 + wn * 32 + nj * 16 + lr;
            bool ok = (f < FDIM);
            float bb = ok ? bias[f] : 0.f;
            #pragma unroll
            for (int mi = 0; mi < 4; ++mi) {
                float z0 = acc[mi][nj][0] + bb;
                float z1 = acc[mi][nj][1] + bb;
                float z2 = acc[mi][nj][2] + bb;
                float z3 = acc[mi][nj][3] + bb;
                unsigned int h01, h23;   // packed bf16 (low = first operand)
                asm("v_cvt_pk_bf16_f32 %0, %1, %2" : "=v"(h01) : "v"(z0), "v"(z1));
                asm("v_cvt_pk_bf16_f32 %0, %1, %2" : "=v"(h23) : "v"(z2), "v"(z3));
                u32x2 st;
                st[0] = key2(h01);
                st[1] = key2(h23);
                if (ok) {
                    int slab = bm * 16 + wm * 8 + mi * 2 + (g >> 1);
                    *(u32x2*)(probs16 + ((size_t)slab * FDIM + f) * 8 + (g & 1) * 4) = st;
                }
            }
        }
    };

    stageA();
    stageB(bq * 4);
    __syncthreads();                     // drains vmcnt -> tiles resident

    f32x4 zero = {0.f, 0.f, 0.f, 0.f};
    for (int t = 0; t < 4; ++t) {
        f32x4 acc[4][2];
        #pragma unroll
        for (int mi = 0; mi < 4; ++mi) { acc[mi][0] = zero; acc[mi][1] = zero; }
        compute(acc);
        if (t < 3) {
            __syncthreads();             // all waves done reading lB(t)
            stageB(bq * 4 + t + 1);      // async B(t+1), hides under epilogue
            epilogue(bq * 4 + t, acc);
            __syncthreads();             // drains vmcnt -> lB(t+1) ready
        } else {
            epilogue(bq * 4 + t, acc);
        }
    }
}

// ---------------------------------------------------------------------------
// segmax15: verified seg12 gather body, TWO slabs per block with a
// double-buffered LDS table (2 x 80000 B = 160000 B <= 160 KiB/CU).
// stage(s0) -> barrier -> issue stage(s1) ASYNC -> compute/store(s0)
// (s1's read traffic hides under s0's gather+write) -> barrier ->
// compute/store(s1). Removes half the serial staging phases (r8 lesson:
// gathers MUST hit LDS; direct-global gather = 208 us, request-bound).
// Cost: 1 block/CU (LDS-capacity) instead of 2.
// ---------------------------------------------------------------------------
__global__ __launch_bounds__(1024) void segmax15_kernel(
    const unsigned short* __restrict__ probs16,
    const int* __restrict__ cur, const unsigned short* __restrict__ ell,
    const int* __restrict__ ovf_cnt, const int* __restrict__ ovf_pairs,
    float* __restrict__ out)
{
    __shared__ unsigned short tbl[2][FDIM * 8];   // 160000 B
    int blk = blockIdx.x;
    int tid = threadIdx.x;
    int novf = *ovf_cnt; if (novf > MAXOVF) novf = MAXOVF;

    auto stage = [&](unsigned short* l, int slab) {
        const unsigned short* src = probs16 + (size_t)slab * FDIM * 8;
        for (int c = tid; c < FDIM; c += 1024)
            gll16(src + (size_t)c * 8, l + (size_t)c * 8);
    };

    auto run = [&](const unsigned short* l, int slab) {
        int b0 = slab * 8;
        for (int p0 = tid * 2; p0 < FDIM; p0 += 2048) {
            int p1 = p0 + 1;
            i32x2 dg = *(const i32x2*)(cur + p0);
            upk4 ea = *(const upk4*)(ell + (size_t)p0 * ELLW);
            upk4 eb = *(const upk4*)(ell + (size_t)p1 * ELLW);
            upk8 ma = *(const upk8*)(l + (size_t)ea[0] * 8);
            upk8 mb = *(const upk8*)(l + (size_t)eb[0] * 8);
            ma = umax8(ma, *(const upk8*)(l + (size_t)ea[1] * 8));
            mb = umax8(mb, *(const upk8*)(l + (size_t)eb[1] * 8));
            ma = umax8(ma, *(const upk8*)(l + (size_t)ea[2] * 8));
            mb = umax8(mb, *(const upk8*)(l + (size_t)eb[2] * 8));
            ma = umax8(ma, *(const upk8*)(l + (size_t)ea[3] * 8));
            mb = umax8(mb, *(const upk8*)(l + (size_t)eb[3] * 8));
            if (dg[0] > 4) {
                upk4 e = *(const upk4*)(ell + (size_t)p0 * ELLW + 4);
                ma = umax8(ma, *(const upk8*)(l + (size_t)e[0] * 8));
                ma = umax8(ma, *(const upk8*)(l + (size_t)e[1] * 8));
                ma = umax8(ma, *(const upk8*)(l + (size_t)e[2] * 8));
                ma = umax8(ma, *(const upk8*)(l + (size_t)e[3] * 8));
            }
            if (dg[1] > 4) {
                upk4 e = *(const upk4*)(ell + (size_t)p1 * ELLW + 4);
                mb = umax8(mb, *(const upk8*)(l + (size_t)e[0] * 8));
                mb = umax8(mb, *(const upk8*)(l + (size_t)e[1] * 8));
                mb = umax8(mb, *(const upk8*)(l + (size_t)e[2] * 8));
                mb = umax8(mb, *(const upk8*)(l + (size_t)e[3] * 8));
            }
            if (dg[0] > 8) {
                upk8 e = *(const upk8*)(ell + (size_t)p0 * ELLW + 8);
                #pragma unroll
                for (int j = 0; j < 8; ++j)
                    ma = umax8(ma, *(const upk8*)(l + (size_t)e[j] * 8));
            }
            if (dg[1] > 8) {
                upk8 e = *(const upk8*)(ell + (size_t)p1 * ELLW + 8);
                #pragma unroll
                for (int j = 0; j < 8; ++j)
                    mb = umax8(mb, *(const upk8*)(l + (size_t)e[j] * 8));
            }
            if (dg[0] > ELLW) {
                for (int i = 0; i < novf; ++i)
                    if (ovf_pairs[2 * i] == p0)
                        ma = umax8(ma, *(const upk8*)(l + (size_t)ovf_pairs[2 * i + 1] * 8));
            }
            if (dg[1] > ELLW) {
                for (int i = 0; i < novf; ++i)
                    if (ovf_pairs[2 * i] == p1)
                        mb = umax8(mb, *(const upk8*)(l + (size_t)ovf_pairs[2 * i + 1] * 8));
            }
            size_t o = (size_t)b0 * FDIM + p0;
            #pragma unroll
            for (int r = 0; r < 8; ++r) {
                f32x2 v2;
                v2[0] = sigk(ma[r]);
                v2[1] = sigk(mb[r]);
                __builtin_nontemporal_store(v2, (f32x2*)(out + o + (size_t)r * FDIM));
            }
        }
    };

    int s0 = blk * 2, s1 = blk * 2 + 1;
    stage(tbl[0], s0);
    __syncthreads();              // tbl[0] resident
    stage(tbl[1], s1);            // async: rides under run(s0)
    run(tbl[0], s0);
    __syncthreads();              // drains s1 staging -> tbl[1] resident
    run(tbl[1], s1);
}

// ---------------------------------------------------------------------------
extern "C" void kernel_launch(void* const* d_in, const int* in_sizes, int n_in,
                              void* d_out, int out_size, void* d_ws, size_t ws_size,
                              hipStream_t stream)
{
    const float* x     = (const float*)d_in[0];
    const float* W     = (const float*)d_in[1];
    const float* bias  = (const float*)d_in[2];
    const int*   epar  = (const int*)d_in[3];
    const int*   echild= (const int*)d_in[4];
    float* out = (float*)d_out;

    char* ws = (char*)d_ws;
    size_t off = 0;
    auto alloc = [&](size_t bytes) { size_t o = off; off = (off + bytes + 255) & ~(size_t)255; return o; };
    size_t o_probs  = alloc((size_t)BDIM * FDIM * 2);    // u16 keys
    size_t o_xb     = alloc((size_t)BDIM * CDIM * 2);
    size_t o_wt     = alloc((size_t)FDIM * CDIM * 2);
    size_t o_ell    = alloc((size_t)FDIM * ELLW * 2);
    size_t o_cur    = alloc((size_t)FDIM * 4);
    size_t o_ovfc   = alloc(4);
    size_t o_ovfp   = alloc((size_t)MAXOVF * 8);
    (void)ws_size; (void)in_sizes; (void)n_in; (void)out_size;

    unsigned short* probs16 = (unsigned short*)(ws + o_probs);
    unsigned short* xb      = (unsigned short*)(ws + o_xb);
    unsigned short* wt      = (unsigned short*)(ws + o_wt);
    unsigned short* ell     = (unsigned short*)(ws + o_ell);
    int* cur      = (int*)(ws + o_cur);
    int* ovf_cnt  = (int*)(ws + o_ovfc);
    int* ovf_pairs= (int*)(ws + o_ovfp);

    prep1_kernel<<<1201, 256, 0, stream>>>(x, W, xb, wt, ell, cur, ovf_cnt);
    prep2_kernel<<<79, 256, 0, stream>>>(epar, echild, cur, ell, ovf_cnt, ovf_pairs);
    gemm8k_kernel<<<128 * NT4, 512, 0, stream>>>(xb, wt, bias, probs16);
    segmax15_kernel<<<BDIM / 16, 1024, 0, stream>>>(probs16, cur, ell,
                                                    ovf_cnt, ovf_pairs, out);
}

// Round 10
// 149.648 us; speedup vs baseline: 1.7121x; 1.0615x over previous
//
#include <hip/hip_runtime.h>
#include <hip/hip_bf16.h>

#define BDIM 16384
#define CDIM 128
#define FDIM 5000
#define EDIM 20000
#define ELLW 16
#define MAXOVF 20000
#define NT4  10       // n-tile QUADS: 40 n-tiles / 4

typedef __attribute__((ext_vector_type(8))) short short8;
typedef __attribute__((ext_vector_type(4))) float f32x4;
typedef __attribute__((ext_vector_type(2))) float f32x2;
typedef __attribute__((ext_vector_type(2))) int i32x2;
typedef __attribute__((ext_vector_type(8))) unsigned short upk8;
typedef __attribute__((ext_vector_type(4))) unsigned short upk4;
typedef __attribute__((ext_vector_type(2))) unsigned int u32x2;

__device__ __forceinline__ unsigned short f2bf(float f) {
    unsigned int u = __builtin_bit_cast(unsigned int, f);
    u = (u + 0x7fffu + ((u >> 16) & 1u)) >> 16;   // RNE
    return (unsigned short)u;
}
__device__ __forceinline__ float bf2f(unsigned short s) {
    unsigned int u = ((unsigned int)s) << 16;
    return __builtin_bit_cast(float, u);
}
__device__ __forceinline__ upk8 umax8(upk8 a, upk8 b) {
#if __has_builtin(__builtin_elementwise_max)
    return __builtin_elementwise_max(a, b);   // 4x v_pk_max_u16
#else
    upk8 r;
    #pragma unroll
    for (int j = 0; j < 8; ++j) r[j] = a[j] > b[j] ? a[j] : b[j];
    return r;
#endif
}
__device__ __forceinline__ upk4 umax4(upk4 a, upk4 b) {
#if __has_builtin(__builtin_elementwise_max)
    return __builtin_elementwise_max(a, b);   // 2x v_pk_max_u16
#else
    upk4 r;
    #pragma unroll
    for (int j = 0; j < 4; ++j) r[j] = a[j] > b[j] ? a[j] : b[j];
    return r;
#endif
}
// single v_rcp_f32. VERIFIED WIN round 2: 178.96 -> 159.24 us.
__device__ __forceinline__ float fast_rcp(float x) {
#if __has_builtin(__builtin_amdgcn_rcpf)
    return __builtin_amdgcn_rcpf(x);
#else
    return 1.0f / x;
#endif
}
// order-preserving u16 key of a bf16 pattern h (per 16-bit half, packed u32).
// VERIFIED WIN round 4: 159.24 -> 153.83 us, absmax 0.0059 -> 0.0039.
__device__ __forceinline__ unsigned int key2(unsigned int h) {
    unsigned int t = (h >> 15) & 0x00010001u;
    return h ^ (t * 0x7FFFu + 0x80008000u);
}
// inverse: k -> bf16 bits
__device__ __forceinline__ unsigned short unkey(unsigned short k) {
    unsigned int s = (k >> 15) & 1u;
    return (unsigned short)(k ^ (0x8000u + ((s ^ 1u) * 0x7FFFu)));
}
__device__ __forceinline__ float sigk(unsigned short k) {
    return fast_rcp(1.0f + __expf(-bf2f(unkey(k))));
}
// async global->LDS, 16B per lane; LDS dest = firstlane base + lane*16
__device__ __forceinline__ void gll16(const unsigned short* g, unsigned short* l) {
    __builtin_amdgcn_global_load_lds(
        (const __attribute__((address_space(1))) void*)g,
        (__attribute__((address_space(3))) void*)l, 16, 0, 0);
}

// ---------------------------------------------------------------------------
// prep1: blocks [0,1024): x f32 -> bf16 (2048 elems/block)
//        blocks [1024,1181): W[k][f] -> Wt[f][k] bf16, LDS-tiled
//        blocks [1181,1201): ELL init (all 16 slots = self), cur=1, ovf=0
// ---------------------------------------------------------------------------
__global__ __launch_bounds__(256) void prep1_kernel(
    const float* __restrict__ x, const float* __restrict__ W,
    unsigned short* __restrict__ xb, unsigned short* __restrict__ wt,
    unsigned short* __restrict__ ell, int* __restrict__ cur,
    int* __restrict__ ovf_cnt)
{
    __shared__ float lt[128][33];
    int bid = blockIdx.x, tid = threadIdx.x;
    if (bid < 1024) {
        size_t base = (size_t)bid * 2048 + (size_t)tid * 8;
        const f32x4* p = (const f32x4*)(x + base);
        f32x4 v0 = p[0], v1 = p[1];
        short8 o;
        o[0] = (short)f2bf(v0[0]); o[1] = (short)f2bf(v0[1]);
        o[2] = (short)f2bf(v0[2]); o[3] = (short)f2bf(v0[3]);
        o[4] = (short)f2bf(v1[0]); o[5] = (short)f2bf(v1[1]);
        o[6] = (short)f2bf(v1[2]); o[7] = (short)f2bf(v1[3]);
        *(short8*)(xb + base) = o;
    } else if (bid < 1181) {
        int f0 = (bid - 1024) * 32;
        int f_l = tid & 31, k0 = (tid >> 5) * 16;
        #pragma unroll
        for (int i = 0; i < 16; ++i) {
            int f = f0 + f_l;
            lt[k0 + i][f_l] = (f < FDIM) ? W[(size_t)(k0 + i) * FDIM + f] : 0.f;
        }
        __syncthreads();
        int f_l2 = tid >> 3, ks = (tid & 7) * 16;
        int f = f0 + f_l2;
        if (f < FDIM) {
            short8 o0, o1;
            #pragma unroll
            for (int j = 0; j < 8; ++j) o0[j] = (short)f2bf(lt[ks + j][f_l2]);
            #pragma unroll
            for (int j = 0; j < 8; ++j) o1[j] = (short)f2bf(lt[ks + 8 + j][f_l2]);
            *(short8*)(wt + (size_t)f * 128 + ks)     = o0;
            *(short8*)(wt + (size_t)f * 128 + ks + 8) = o1;
        }
    } else {
        int p = (bid - 1181) * 256 + tid;
        if (p < FDIM) {
            upk8 s;
            #pragma unroll
            for (int j = 0; j < 8; ++j) s[j] = (unsigned short)p;
            *(upk8*)(ell + (size_t)p * ELLW)     = s;
            *(upk8*)(ell + (size_t)p * ELLW + 8) = s;
            cur[p] = 1;
        }
        if (p == FDIM) *ovf_cnt = 0;
    }
}

// ---------------------------------------------------------------------------
// prep2: scatter children into ELL slots 1.. (order irrelevant: max).
// ---------------------------------------------------------------------------
__global__ __launch_bounds__(256) void prep2_kernel(
    const int* __restrict__ epar, const int* __restrict__ echild,
    int* __restrict__ cur, unsigned short* __restrict__ ell,
    int* __restrict__ ovf_cnt, int* __restrict__ ovf_pairs)
{
    int i = blockIdx.x * 256 + threadIdx.x;
    if (i < EDIM) {
        int p = epar[i], c = echild[i];
        if (p != c) {
            int pos = atomicAdd(&cur[p], 1);
            if (pos < ELLW) {
                ell[(size_t)p * ELLW + pos] = (unsigned short)c;
            } else {
                int j = atomicAdd(ovf_cnt, 1);
                if (j < MAXOVF) { ovf_pairs[2 * j] = p; ovf_pairs[2 * j + 1] = c; }
            }
        }
    }
}

// ---------------------------------------------------------------------------
// gemm8h: EXACT r4-verified structure; ONLY the probs16 store ADDRESS
// changes. The u32x2 each lane writes is precisely the (g&1)-half (4 batch
// elems) of a slab row -> write it to a HALF-SLAB-contiguous layout
// [slab*2 + (g&1)][FDIM][4] u16 so segmax can gll16-stage 40KB half-tables
// and gather 8B rows (2 banks/lane instead of 4 -> ~halved bank conflicts,
// the one measured seg cost: r3's SQ_LDS_BANK_CONFLICT ~1e7 cyc).
// ---------------------------------------------------------------------------
__global__ __launch_bounds__(512, 4) void gemm8h_kernel(
    const unsigned short* __restrict__ xb,   // [BDIM][128] bf16
    const unsigned short* __restrict__ wt,   // [FDIM][128] bf16
    const float* __restrict__ bias,
    unsigned short* __restrict__ probs16)    // [BDIM/8*2][FDIM][4] u16 keys
{
    __shared__ unsigned short lA[128 * 128];
    __shared__ unsigned short lB[128 * 128];

    int bid0 = blockIdx.x;
    int bid  = (bid0 & 7) * (128 * NT4 / 8) + (bid0 >> 3);   // XCD swizzle
    int bm = bid / NT4, bq = bid % NT4;
    int tid = threadIdx.x;
    int lane = tid & 63, w = tid >> 6;       // 8 waves
    int wm = w >> 2, wn = w & 3;
    int g = lane >> 4, lr = lane & 15;
    int lrow = lane >> 4;                    // row within 4-row chunk
    int lcol = (lane & 15) << 4;             // byte col

    auto stageA = [&]() {
        #pragma unroll
        for (int it = 0; it < 4; ++it) {
            int ci = w * 4 + it;             // chunk 0..31
            int row = ci * 4 + lrow;
            int sw = lcol ^ ((row & 7) << 4);
            gll16(xb + ((size_t)(bm * 128 + row) << 7) + (sw >> 1),
                  lA + ci * 512);
        }
    };
    auto stageB = [&](int bn) {
        #pragma unroll
        for (int it = 0; it < 4; ++it) {
            int ci = w * 4 + it;
            int row = ci * 4 + lrow;
            int sw = lcol ^ ((row & 7) << 4);
            gll16(wt + ((size_t)(bn * 128 + row) << 7) + (sw >> 1),
                  lB + ci * 512);
        }
    };
    auto compute = [&](f32x4 (&acc)[4][2]) {
        #pragma unroll
        for (int ks = 0; ks < 4; ++ks) {
            int cbk = ks * 64 + g * 16;
            short8 af[4], bf[2];
            #pragma unroll
            for (int mi = 0; mi < 4; ++mi) {
                int row = wm * 64 + mi * 16 + lr;
                af[mi] = *(const short8*)((const char*)lA + row * 256 + (cbk ^ ((row & 7) << 4)));
            }
            #pragma unroll
            for (int nj = 0; nj < 2; ++nj) {
                int row = wn * 32 + nj * 16 + lr;
                bf[nj] = *(const short8*)((const char*)lB + row * 256 + (cbk ^ ((row & 7) << 4)));
            }
            #pragma unroll
            for (int mi = 0; mi < 4; ++mi)
                #pragma unroll
                for (int nj = 0; nj < 2; ++nj)
                    acc[mi][nj] = __builtin_amdgcn_mfma_f32_16x16x32_bf16(
                        af[mi], bf[nj], acc[mi][nj], 0, 0, 0);
        }
    };
    auto epilogue = [&](int bn, f32x4 (&acc)[4][2]) {
        #pragma unroll
        for (int nj = 0; nj < 2; ++nj) {
            int f = bn * 128 + wn * 32 + nj * 16 + lr;
            bool ok = (f < FDIM);
            float bb = ok ? bias[f] : 0.f;
            #pragma unroll
            for (int mi = 0; mi < 4; ++mi) {
                float z0 = acc[mi][nj][0] + bb;
                float z1 = acc[mi][nj][1] + bb;
                float z2 = acc[mi][nj][2] + bb;
                float z3 = acc[mi][nj][3] + bb;
                unsigned int h01, h23;   // packed bf16 (low = first operand)
                asm("v_cvt_pk_bf16_f32 %0, %1, %2" : "=v"(h01) : "v"(z0), "v"(z1));
                asm("v_cvt_pk_bf16_f32 %0, %1, %2" : "=v"(h23) : "v"(z2), "v"(z3));
                u32x2 st;
                st[0] = key2(h01);
                st[1] = key2(h23);
                if (ok) {
                    int slab = bm * 16 + wm * 8 + mi * 2 + (g >> 1);
                    int grp  = slab * 2 + (g & 1);   // half-slab group
                    *(u32x2*)(probs16 + ((size_t)grp * FDIM + f) * 4) = st;
                }
            }
        }
    };

    stageA();
    stageB(bq * 4);
    __syncthreads();                     // drains vmcnt -> tiles resident

    f32x4 zero = {0.f, 0.f, 0.f, 0.f};
    for (int t = 0; t < 4; ++t) {
        f32x4 acc[4][2];
        #pragma unroll
        for (int mi = 0; mi < 4; ++mi) { acc[mi][0] = zero; acc[mi][1] = zero; }
        compute(acc);
        if (t < 3) {
            __syncthreads();             // all waves done reading lB(t)
            stageB(bq * 4 + t + 1);      // async B(t+1), hides under epilogue
            epilogue(bq * 4 + t, acc);
            __syncthreads();             // drains vmcnt -> lB(t+1) ready
        } else {
            epilogue(bq * 4 + t, acc);
        }
    }
}

// ---------------------------------------------------------------------------
// segmax16: half-slab blocks (4 batch rows, 40000B table). Gathers are b64
// over 8B rows -> 2 banks/lane -> ~4 req/bank -> 1.58x serialization (m136)
// vs the 16B/2.94x of seg12. 4096 blocks (16/CU, 2 resident) -> finer
// phase stagger. Max logic / ELL walk / sigmoid identical -> bit-exact.
// ---------------------------------------------------------------------------
__global__ __launch_bounds__(1024) void segmax16_kernel(
    const unsigned short* __restrict__ probs16,  // [4096][FDIM][4] u16
    const int* __restrict__ cur, const unsigned short* __restrict__ ell,
    const int* __restrict__ ovf_cnt, const int* __restrict__ ovf_pairs,
    float* __restrict__ out)
{
    __shared__ unsigned short l[FDIM * 4];   // 40000 B of u16 keys
    int grp = blockIdx.x;                    // half-slab group
    int b0 = (grp >> 1) * 8 + (grp & 1) * 4; // first of 4 batch rows
    int tid = threadIdx.x;
    const unsigned short* src = probs16 + (size_t)grp * FDIM * 4;

    for (int c = tid; c < FDIM / 2; c += 1024) {
        // 16B = two 8B rows; contiguous in the half-slab layout
        gll16(src + (size_t)c * 8, l + (size_t)c * 8);
    }
    __syncthreads();                         // drains vmcnt -> table resident

    int novf = *ovf_cnt; if (novf > MAXOVF) novf = MAXOVF;

    for (int p0 = tid * 2; p0 < FDIM; p0 += 2048) {
        int p1 = p0 + 1;
        i32x2 dg = *(const i32x2*)(cur + p0);
        upk4 ea = *(const upk4*)(ell + (size_t)p0 * ELLW);
        upk4 eb = *(const upk4*)(ell + (size_t)p1 * ELLW);
        upk4 ma = *(const upk4*)(l + (size_t)ea[0] * 4);
        upk4 mb = *(const upk4*)(l + (size_t)eb[0] * 4);
        ma = umax4(ma, *(const upk4*)(l + (size_t)ea[1] * 4));
        mb = umax4(mb, *(const upk4*)(l + (size_t)eb[1] * 4));
        ma = umax4(ma, *(const upk4*)(l + (size_t)ea[2] * 4));
        mb = umax4(mb, *(const upk4*)(l + (size_t)eb[2] * 4));
        ma = umax4(ma, *(const upk4*)(l + (size_t)ea[3] * 4));
        mb = umax4(mb, *(const upk4*)(l + (size_t)eb[3] * 4));
        if (dg[0] > 4) {
            upk4 e = *(const upk4*)(ell + (size_t)p0 * ELLW + 4);
            ma = umax4(ma, *(const upk4*)(l + (size_t)e[0] * 4));
            ma = umax4(ma, *(const upk4*)(l + (size_t)e[1] * 4));
            ma = umax4(ma, *(const upk4*)(l + (size_t)e[2] * 4));
            ma = umax4(ma, *(const upk4*)(l + (size_t)e[3] * 4));
        }
        if (dg[1] > 4) {
            upk4 e = *(const upk4*)(ell + (size_t)p1 * ELLW + 4);
            mb = umax4(mb, *(const upk4*)(l + (size_t)e[0] * 4));
            mb = umax4(mb, *(const upk4*)(l + (size_t)e[1] * 4));
            mb = umax4(mb, *(const upk4*)(l + (size_t)e[2] * 4));
            mb = umax4(mb, *(const upk4*)(l + (size_t)e[3] * 4));
        }
        if (dg[0] > 8) {
            upk8 e = *(const upk8*)(ell + (size_t)p0 * ELLW + 8);
            #pragma unroll
            for (int j = 0; j < 8; ++j)
                ma = umax4(ma, *(const upk4*)(l + (size_t)e[j] * 4));
        }
        if (dg[1] > 8) {
            upk8 e = *(const upk8*)(ell + (size_t)p1 * ELLW + 8);
            #pragma unroll
            for (int j = 0; j < 8; ++j)
                mb = umax4(mb, *(const upk4*)(l + (size_t)e[j] * 4));
        }
        if (dg[0] > ELLW) {
            for (int i = 0; i < novf; ++i)
                if (ovf_pairs[2 * i] == p0)
                    ma = umax4(ma, *(const upk4*)(l + (size_t)ovf_pairs[2 * i + 1] * 4));
        }
        if (dg[1] > ELLW) {
            for (int i = 0; i < novf; ++i)
                if (ovf_pairs[2 * i] == p1)
                    mb = umax4(mb, *(const upk4*)(l + (size_t)ovf_pairs[2 * i + 1] * 4));
        }
        size_t o = (size_t)b0 * FDIM + p0;
        #pragma unroll
        for (int r = 0; r < 4; ++r) {
            f32x2 v2;
            v2[0] = sigk(ma[r]);
            v2[1] = sigk(mb[r]);
            __builtin_nontemporal_store(v2, (f32x2*)(out + o + (size_t)r * FDIM));
        }
    }
}

// ---------------------------------------------------------------------------
extern "C" void kernel_launch(void* const* d_in, const int* in_sizes, int n_in,
                              void* d_out, int out_size, void* d_ws, size_t ws_size,
                              hipStream_t stream)
{
    const float* x     = (const float*)d_in[0];
    const float* W     = (const float*)d_in[1];
    const float* bias  = (const float*)d_in[2];
    const int*   epar  = (const int*)d_in[3];
    const int*   echild= (const int*)d_in[4];
    float* out = (float*)d_out;

    char* ws = (char*)d_ws;
    size_t off = 0;
    auto alloc = [&](size_t bytes) { size_t o = off; off = (off + bytes + 255) & ~(size_t)255; return o; };
    size_t o_probs  = alloc((size_t)BDIM * FDIM * 2);    // u16 keys (half-slab layout)
    size_t o_xb     = alloc((size_t)BDIM * CDIM * 2);
    size_t o_wt     = alloc((size_t)FDIM * CDIM * 2);
    size_t o_ell    = alloc((size_t)FDIM * ELLW * 2);
    size_t o_cur    = alloc((size_t)FDIM * 4);
    size_t o_ovfc   = alloc(4);
    size_t o_ovfp   = alloc((size_t)MAXOVF * 8);
    (void)ws_size; (void)in_sizes; (void)n_in; (void)out_size;

    unsigned short* probs16 = (unsigned short*)(ws + o_probs);
    unsigned short* xb      = (unsigned short*)(ws + o_xb);
    unsigned short* wt      = (unsigned short*)(ws + o_wt);
    unsigned short* ell     = (unsigned short*)(ws + o_ell);
    int* cur      = (int*)(ws + o_cur);
    int* ovf_cnt  = (int*)(ws + o_ovfc);
    int* ovf_pairs= (int*)(ws + o_ovfp);

    prep1_kernel<<<1201, 256, 0, stream>>>(x, W, xb, wt, ell, cur, ovf_cnt);
    prep2_kernel<<<79, 256, 0, stream>>>(epar, echild, cur, ell, ovf_cnt, ovf_pairs);
    gemm8h_kernel<<<128 * NT4, 512, 0, stream>>>(xb, wt, bias, probs16);
    segmax16_kernel<<<BDIM / 8 * 2, 1024, 0, stream>>>(probs16, cur, ell,
                                                       ovf_cnt, ovf_pairs, out);
}

// Round 11
// 148.209 us; speedup vs baseline: 1.7287x; 1.0097x over previous
//
#include <hip/hip_runtime.h>
#include <hip/hip_bf16.h>

#define BDIM 16384
#define CDIM 128
#define FDIM 5000
#define EDIM 20000
#define ELLW 16
#define MAXOVF 20000
#define NT4  10       // n-tile QUADS: 40 n-tiles / 4

typedef __attribute__((ext_vector_type(8))) short short8;
typedef __attribute__((ext_vector_type(4))) float f32x4;
typedef __attribute__((ext_vector_type(2))) float f32x2;
typedef __attribute__((ext_vector_type(2))) int i32x2;
typedef __attribute__((ext_vector_type(8))) unsigned short upk8;
typedef __attribute__((ext_vector_type(4))) unsigned short upk4;
typedef __attribute__((ext_vector_type(2))) unsigned int u32x2;

__device__ __forceinline__ unsigned short f2bf(float f) {
    unsigned int u = __builtin_bit_cast(unsigned int, f);
    u = (u + 0x7fffu + ((u >> 16) & 1u)) >> 16;   // RNE
    return (unsigned short)u;
}
__device__ __forceinline__ float bf2f(unsigned short s) {
    unsigned int u = ((unsigned int)s) << 16;
    return __builtin_bit_cast(float, u);
}
__device__ __forceinline__ upk4 umax4(upk4 a, upk4 b) {
#if __has_builtin(__builtin_elementwise_max)
    return __builtin_elementwise_max(a, b);   // 2x v_pk_max_u16
#else
    upk4 r;
    #pragma unroll
    for (int j = 0; j < 4; ++j) r[j] = a[j] > b[j] ? a[j] : b[j];
    return r;
#endif
}
// single v_rcp_f32. VERIFIED WIN round 2: 178.96 -> 159.24 us.
__device__ __forceinline__ float fast_rcp(float x) {
#if __has_builtin(__builtin_amdgcn_rcpf)
    return __builtin_amdgcn_rcpf(x);
#else
    return 1.0f / x;
#endif
}
// order-preserving u16 key of a bf16 pattern h (per 16-bit half, packed u32).
// VERIFIED WIN round 4: 159.24 -> 153.83 us, absmax 0.0059 -> 0.0039.
__device__ __forceinline__ unsigned int key2(unsigned int h) {
    unsigned int t = (h >> 15) & 0x00010001u;
    return h ^ (t * 0x7FFFu + 0x80008000u);
}
// inverse: k -> bf16 bits
__device__ __forceinline__ unsigned short unkey(unsigned short k) {
    unsigned int s = (k >> 15) & 1u;
    return (unsigned short)(k ^ (0x8000u + ((s ^ 1u) * 0x7FFFu)));
}
__device__ __forceinline__ float sigk(unsigned short k) {
    return fast_rcp(1.0f + __expf(-bf2f(unkey(k))));
}
// async global->LDS, 16B per lane; LDS dest = firstlane base + lane*16
__device__ __forceinline__ void gll16(const unsigned short* g, unsigned short* l) {
    __builtin_amdgcn_global_load_lds(
        (const __attribute__((address_space(1))) void*)g,
        (__attribute__((address_space(3))) void*)l, 16, 0, 0);
}

// ---------------------------------------------------------------------------
// prep1: blocks [0,1024): x f32 -> bf16 (2048 elems/block)
//        blocks [1024,1181): W[k][f] -> Wt[f][k] bf16, LDS-tiled
//        blocks [1181,1201): ELL init (all 16 slots = self), cur=1, ovf=0
// ---------------------------------------------------------------------------
__global__ __launch_bounds__(256) void prep1_kernel(
    const float* __restrict__ x, const float* __restrict__ W,
    unsigned short* __restrict__ xb, unsigned short* __restrict__ wt,
    unsigned short* __restrict__ ell, int* __restrict__ cur,
    int* __restrict__ ovf_cnt)
{
    __shared__ float lt[128][33];
    int bid = blockIdx.x, tid = threadIdx.x;
    if (bid < 1024) {
        size_t base = (size_t)bid * 2048 + (size_t)tid * 8;
        const f32x4* p = (const f32x4*)(x + base);
        f32x4 v0 = p[0], v1 = p[1];
        short8 o;
        o[0] = (short)f2bf(v0[0]); o[1] = (short)f2bf(v0[1]);
        o[2] = (short)f2bf(v0[2]); o[3] = (short)f2bf(v0[3]);
        o[4] = (short)f2bf(v1[0]); o[5] = (short)f2bf(v1[1]);
        o[6] = (short)f2bf(v1[2]); o[7] = (short)f2bf(v1[3]);
        *(short8*)(xb + base) = o;
    } else if (bid < 1181) {
        int f0 = (bid - 1024) * 32;
        int f_l = tid & 31, k0 = (tid >> 5) * 16;
        #pragma unroll
        for (int i = 0; i < 16; ++i) {
            int f = f0 + f_l;
            lt[k0 + i][f_l] = (f < FDIM) ? W[(size_t)(k0 + i) * FDIM + f] : 0.f;
        }
        __syncthreads();
        int f_l2 = tid >> 3, ks = (tid & 7) * 16;
        int f = f0 + f_l2;
        if (f < FDIM) {
            short8 o0, o1;
            #pragma unroll
            for (int j = 0; j < 8; ++j) o0[j] = (short)f2bf(lt[ks + j][f_l2]);
            #pragma unroll
            for (int j = 0; j < 8; ++j) o1[j] = (short)f2bf(lt[ks + 8 + j][f_l2]);
            *(short8*)(wt + (size_t)f * 128 + ks)     = o0;
            *(short8*)(wt + (size_t)f * 128 + ks + 8) = o1;
        }
    } else {
        int p = (bid - 1181) * 256 + tid;
        if (p < FDIM) {
            upk8 s;
            #pragma unroll
            for (int j = 0; j < 8; ++j) s[j] = (unsigned short)p;
            *(upk8*)(ell + (size_t)p * ELLW)     = s;
            *(upk8*)(ell + (size_t)p * ELLW + 8) = s;
            cur[p] = 1;
        }
        if (p == FDIM) *ovf_cnt = 0;
    }
}

// ---------------------------------------------------------------------------
// prep2: scatter children into ELL slots 1.. (order irrelevant: max).
// ---------------------------------------------------------------------------
__global__ __launch_bounds__(256) void prep2_kernel(
    const int* __restrict__ epar, const int* __restrict__ echild,
    int* __restrict__ cur, unsigned short* __restrict__ ell,
    int* __restrict__ ovf_cnt, int* __restrict__ ovf_pairs)
{
    int i = blockIdx.x * 256 + threadIdx.x;
    if (i < EDIM) {
        int p = epar[i], c = echild[i];
        if (p != c) {
            int pos = atomicAdd(&cur[p], 1);
            if (pos < ELLW) {
                ell[(size_t)p * ELLW + pos] = (unsigned short)c;
            } else {
                int j = atomicAdd(ovf_cnt, 1);
                if (j < MAXOVF) { ovf_pairs[2 * j] = p; ovf_pairs[2 * j + 1] = c; }
            }
        }
    }
}

// ---------------------------------------------------------------------------
// prep3: counting-sort parents by (capped) degree -> dgp[i] = perm<<8 | dg,
// and materialize permuted ELL rows (ellp[i][16] = ell[perm[i]][16]) so
// seg's index loads stay coalesced. Single block (needs block-wide sync
// between histogram/scan/scatter). ~2-3 us.
// ---------------------------------------------------------------------------
__global__ __launch_bounds__(1024) void prep3_kernel(
    const int* __restrict__ cur, const unsigned short* __restrict__ ell,
    unsigned int* __restrict__ dgp, unsigned short* __restrict__ ellp)
{
    __shared__ int hist[32];
    __shared__ int base[32];
    int tid = threadIdx.x;
    if (tid < 32) hist[tid] = 0;
    __syncthreads();
    for (int p = tid; p < FDIM; p += 1024) {
        int d = cur[p]; if (d > 31) d = 31;
        atomicAdd(&hist[d], 1);
    }
    __syncthreads();
    if (tid == 0) {
        int acc = 0;
        for (int b = 0; b < 32; ++b) { base[b] = acc; acc += hist[b]; }
    }
    __syncthreads();
    for (int p = tid; p < FDIM; p += 1024) {
        int d = cur[p]; if (d > 31) d = 31;
        int pos = atomicAdd(&base[d], 1);
        int dcap = cur[p]; if (dcap > 255) dcap = 255;
        dgp[pos] = ((unsigned int)p << 8) | (unsigned int)dcap;
    }
    __syncthreads();   // dgp visible block-wide
    for (int i = tid; i < FDIM; i += 1024) {
        int pr = (int)(dgp[i] >> 8);
        upk8 lo = *(const upk8*)(ell + (size_t)pr * ELLW);
        upk8 hi = *(const upk8*)(ell + (size_t)pr * ELLW + 8);
        *(upk8*)(ellp + (size_t)i * ELLW)     = lo;
        *(upk8*)(ellp + (size_t)i * ELLW + 8) = hi;
    }
}

// ---------------------------------------------------------------------------
// gemm8h: EXACT r10-verified version (149.65 us pipeline). Half-slab
// probs16 layout [slab*2+(g&1)][FDIM][4].
// ---------------------------------------------------------------------------
__global__ __launch_bounds__(512, 4) void gemm8h_kernel(
    const unsigned short* __restrict__ xb,   // [BDIM][128] bf16
    const unsigned short* __restrict__ wt,   // [FDIM][128] bf16
    const float* __restrict__ bias,
    unsigned short* __restrict__ probs16)    // [BDIM/8*2][FDIM][4] u16 keys
{
    __shared__ unsigned short lA[128 * 128];
    __shared__ unsigned short lB[128 * 128];

    int bid0 = blockIdx.x;
    int bid  = (bid0 & 7) * (128 * NT4 / 8) + (bid0 >> 3);   // XCD swizzle
    int bm = bid / NT4, bq = bid % NT4;
    int tid = threadIdx.x;
    int lane = tid & 63, w = tid >> 6;       // 8 waves
    int wm = w >> 2, wn = w & 3;
    int g = lane >> 4, lr = lane & 15;
    int lrow = lane >> 4;                    // row within 4-row chunk
    int lcol = (lane & 15) << 4;             // byte col

    auto stageA = [&]() {
        #pragma unroll
        for (int it = 0; it < 4; ++it) {
            int ci = w * 4 + it;             // chunk 0..31
            int row = ci * 4 + lrow;
            int sw = lcol ^ ((row & 7) << 4);
            gll16(xb + ((size_t)(bm * 128 + row) << 7) + (sw >> 1),
                  lA + ci * 512);
        }
    };
    auto stageB = [&](int bn) {
        #pragma unroll
        for (int it = 0; it < 4; ++it) {
            int ci = w * 4 + it;
            int row = ci * 4 + lrow;
            int sw = lcol ^ ((row & 7) << 4);
            gll16(wt + ((size_t)(bn * 128 + row) << 7) + (sw >> 1),
                  lB + ci * 512);
        }
    };
    auto compute = [&](f32x4 (&acc)[4][2]) {
        #pragma unroll
        for (int ks = 0; ks < 4; ++ks) {
            int cbk = ks * 64 + g * 16;
            short8 af[4], bf[2];
            #pragma unroll
            for (int mi = 0; mi < 4; ++mi) {
                int row = wm * 64 + mi * 16 + lr;
                af[mi] = *(const short8*)((const char*)lA + row * 256 + (cbk ^ ((row & 7) << 4)));
            }
            #pragma unroll
            for (int nj = 0; nj < 2; ++nj) {
                int row = wn * 32 + nj * 16 + lr;
                bf[nj] = *(const short8*)((const char*)lB + row * 256 + (cbk ^ ((row & 7) << 4)));
            }
            #pragma unroll
            for (int mi = 0; mi < 4; ++mi)
                #pragma unroll
                for (int nj = 0; nj < 2; ++nj)
                    acc[mi][nj] = __builtin_amdgcn_mfma_f32_16x16x32_bf16(
                        af[mi], bf[nj], acc[mi][nj], 0, 0, 0);
        }
    };
    auto epilogue = [&](int bn, f32x4 (&acc)[4][2]) {
        #pragma unroll
        for (int nj = 0; nj < 2; ++nj) {
            int f = bn * 128 + wn * 32 + nj * 16 + lr;
            bool ok = (f < FDIM);
            float bb = ok ? bias[f] : 0.f;
            #pragma unroll
            for (int mi = 0; mi < 4; ++mi) {
                float z0 = acc[mi][nj][0] + bb;
                float z1 = acc[mi][nj][1] + bb;
                float z2 = acc[mi][nj][2] + bb;
                float z3 = acc[mi][nj][3] + bb;
                unsigned int h01, h23;   // packed bf16 (low = first operand)
                asm("v_cvt_pk_bf16_f32 %0, %1, %2" : "=v"(h01) : "v"(z0), "v"(z1));
                asm("v_cvt_pk_bf16_f32 %0, %1, %2" : "=v"(h23) : "v"(z2), "v"(z3));
                u32x2 st;
                st[0] = key2(h01);
                st[1] = key2(h23);
                if (ok) {
                    int slab = bm * 16 + wm * 8 + mi * 2 + (g >> 1);
                    int grp  = slab * 2 + (g & 1);   // half-slab group
                    *(u32x2*)(probs16 + ((size_t)grp * FDIM + f) * 4) = st;
                }
            }
        }
    };

    stageA();
    stageB(bq * 4);
    __syncthreads();                     // drains vmcnt -> tiles resident

    f32x4 zero = {0.f, 0.f, 0.f, 0.f};
    for (int t = 0; t < 4; ++t) {
        f32x4 acc[4][2];
        #pragma unroll
        for (int mi = 0; mi < 4; ++mi) { acc[mi][0] = zero; acc[mi][1] = zero; }
        compute(acc);
        if (t < 3) {
            __syncthreads();             // all waves done reading lB(t)
            stageB(bq * 4 + t + 1);      // async B(t+1), hides under epilogue
            epilogue(bq * 4 + t, acc);
            __syncthreads();             // drains vmcnt -> lB(t+1) ready
        } else {
            epilogue(bq * 4 + t, acc);
        }
    }
}

// ---------------------------------------------------------------------------
// segmax17: = r10-verified seg16 gather body, but parents walked in
// DEGREE-SORTED order (dgp/ellp from prep3) -> wave-uniform dg -> the
// dg>4 / dg>8 branches execute in ~35% / ~1% of waves instead of ~100% /
// ~79% (wave-divergence made every wave walk all slots). Results exchanged
// through a 40KB LDS xchg[] keyed by original parent, then a canonical
// coalesced phase does sigmoid + f32x4 stores (4 adjacent parents/thread).
// Bit-exact vs seg16 (pure reordering). LDS 80000B -> still 2 blocks/CU.
// ---------------------------------------------------------------------------
__global__ __launch_bounds__(1024) void segmax17_kernel(
    const unsigned short* __restrict__ probs16,  // [4096][FDIM][4] u16
    const unsigned int* __restrict__ dgp,        // [FDIM] perm<<8|dg (sorted)
    const unsigned short* __restrict__ ellp,     // [FDIM][16] permuted ELL
    const int* __restrict__ ovf_cnt, const int* __restrict__ ovf_pairs,
    float* __restrict__ out)
{
    __shared__ unsigned short l[FDIM * 4];       // 40000 B table
    __shared__ unsigned short xchg[FDIM * 4];    // 40000 B maxkey exchange
    int grp = blockIdx.x;                        // half-slab group
    int b0 = (grp >> 1) * 8 + (grp & 1) * 4;     // first of 4 batch rows
    int tid = threadIdx.x;
    const unsigned short* src = probs16 + (size_t)grp * FDIM * 4;

    for (int c = tid; c < FDIM / 2; c += 1024) {
        gll16(src + (size_t)c * 8, l + (size_t)c * 8);
    }
    __syncthreads();                             // table resident

    int novf = *ovf_cnt; if (novf > MAXOVF) novf = MAXOVF;

    // ---- gather phase: sorted order, 2 slots/thread/iter ----
    for (int w0 = tid * 2; w0 < FDIM; w0 += 2048) {
        int w1 = w0 + 1;
        u32x2 dv = *(const u32x2*)(dgp + w0);
        int pa = (int)(dv[0] >> 8), da = (int)(dv[0] & 255u);
        int pb = (int)(dv[1] >> 8), db = (int)(dv[1] & 255u);
        upk8 ea = *(const upk8*)(ellp + (size_t)w0 * ELLW);   // slots 0-7
        upk8 eb = *(const upk8*)(ellp + (size_t)w1 * ELLW);
        upk4 ma = *(const upk4*)(l + (size_t)ea[0] * 4);
        upk4 mb = *(const upk4*)(l + (size_t)eb[0] * 4);
        ma = umax4(ma, *(const upk4*)(l + (size_t)ea[1] * 4));
        mb = umax4(mb, *(const upk4*)(l + (size_t)eb[1] * 4));
        ma = umax4(ma, *(const upk4*)(l + (size_t)ea[2] * 4));
        mb = umax4(mb, *(const upk4*)(l + (size_t)eb[2] * 4));
        ma = umax4(ma, *(const upk4*)(l + (size_t)ea[3] * 4));
        mb = umax4(mb, *(const upk4*)(l + (size_t)eb[3] * 4));
        if (da > 4) {
            ma = umax4(ma, *(const upk4*)(l + (size_t)ea[4] * 4));
            ma = umax4(ma, *(const upk4*)(l + (size_t)ea[5] * 4));
            ma = umax4(ma, *(const upk4*)(l + (size_t)ea[6] * 4));
            ma = umax4(ma, *(const upk4*)(l + (size_t)ea[7] * 4));
        }
        if (db > 4) {
            mb = umax4(mb, *(const upk4*)(l + (size_t)eb[4] * 4));
            mb = umax4(mb, *(const upk4*)(l + (size_t)eb[5] * 4));
            mb = umax4(mb, *(const upk4*)(l + (size_t)eb[6] * 4));
            mb = umax4(mb, *(const upk4*)(l + (size_t)eb[7] * 4));
        }
        if (da > 8) {
            upk8 e = *(const upk8*)(ellp + (size_t)w0 * ELLW + 8);
            #pragma unroll
            for (int k = 0; k < 8; ++k)
                ma = umax4(ma, *(const upk4*)(l + (size_t)e[k] * 4));
        }
        if (db > 8) {
            upk8 e = *(const upk8*)(ellp + (size_t)w1 * ELLW + 8);
            #pragma unroll
            for (int k = 0; k < 8; ++k)
                mb = umax4(mb, *(const upk4*)(l + (size_t)e[k] * 4));
        }
        if (da > ELLW) {
            for (int i = 0; i < novf; ++i)
                if (ovf_pairs[2 * i] == pa)
                    ma = umax4(ma, *(const upk4*)(l + (size_t)ovf_pairs[2 * i + 1] * 4));
        }
        if (db > ELLW) {
            for (int i = 0; i < novf; ++i)
                if (ovf_pairs[2 * i] == pb)
                    mb = umax4(mb, *(const upk4*)(l + (size_t)ovf_pairs[2 * i + 1] * 4));
        }
        *(upk4*)(xchg + (size_t)pa * 4) = ma;
        *(upk4*)(xchg + (size_t)pb * 4) = mb;
    }
    __syncthreads();                             // xchg complete

    // ---- canonical phase: 4 adjacent parents/thread, f32x4 stores ----
    for (int p0 = tid * 4; p0 < FDIM; p0 += 4096) {   // 5000%4==0
        upk4 m0 = *(const upk4*)(xchg + (size_t)p0 * 4);
        upk4 m1 = *(const upk4*)(xchg + (size_t)(p0 + 1) * 4);
        upk4 m2 = *(const upk4*)(xchg + (size_t)(p0 + 2) * 4);
        upk4 m3 = *(const upk4*)(xchg + (size_t)(p0 + 3) * 4);
        size_t o = (size_t)b0 * FDIM + p0;
        #pragma unroll
        for (int r = 0; r < 4; ++r) {
            f32x4 v4;
            v4[0] = sigk(m0[r]);
            v4[1] = sigk(m1[r]);
            v4[2] = sigk(m2[r]);
            v4[3] = sigk(m3[r]);
            __builtin_nontemporal_store(v4, (f32x4*)(out + o + (size_t)r * FDIM));
        }
    }
}

// ---------------------------------------------------------------------------
extern "C" void kernel_launch(void* const* d_in, const int* in_sizes, int n_in,
                              void* d_out, int out_size, void* d_ws, size_t ws_size,
                              hipStream_t stream)
{
    const float* x     = (const float*)d_in[0];
    const float* W     = (const float*)d_in[1];
    const float* bias  = (const float*)d_in[2];
    const int*   epar  = (const int*)d_in[3];
    const int*   echild= (const int*)d_in[4];
    float* out = (float*)d_out;

    char* ws = (char*)d_ws;
    size_t off = 0;
    auto alloc = [&](size_t bytes) { size_t o = off; off = (off + bytes + 255) & ~(size_t)255; return o; };
    size_t o_probs  = alloc((size_t)BDIM * FDIM * 2);    // u16 keys (half-slab layout)
    size_t o_xb     = alloc((size_t)BDIM * CDIM * 2);
    size_t o_wt     = alloc((size_t)FDIM * CDIM * 2);
    size_t o_ell    = alloc((size_t)FDIM * ELLW * 2);
    size_t o_cur    = alloc((size_t)FDIM * 4);
    size_t o_ovfc   = alloc(4);
    size_t o_ovfp   = alloc((size_t)MAXOVF * 8);
    size_t o_dgp    = alloc((size_t)FDIM * 4);
    size_t o_ellp   = alloc((size_t)FDIM * ELLW * 2);
    (void)ws_size; (void)in_sizes; (void)n_in; (void)out_size;

    unsigned short* probs16 = (unsigned short*)(ws + o_probs);
    unsigned short* xb      = (unsigned short*)(ws + o_xb);
    unsigned short* wt      = (unsigned short*)(ws + o_wt);
    unsigned short* ell     = (unsigned short*)(ws + o_ell);
    int* cur      = (int*)(ws + o_cur);
    int* ovf_cnt  = (int*)(ws + o_ovfc);
    int* ovf_pairs= (int*)(ws + o_ovfp);
    unsigned int*   dgp  = (unsigned int*)(ws + o_dgp);
    unsigned short* ellp = (unsigned short*)(ws + o_ellp);

    prep1_kernel<<<1201, 256, 0, stream>>>(x, W, xb, wt, ell, cur, ovf_cnt);
    prep2_kernel<<<79, 256, 0, stream>>>(epar, echild, cur, ell, ovf_cnt, ovf_pairs);
    prep3_kernel<<<1, 1024, 0, stream>>>(cur, ell, dgp, ellp);
    gemm8h_kernel<<<128 * NT4, 512, 0, stream>>>(xb, wt, bias, probs16);
    segmax17_kernel<<<BDIM / 8 * 2, 1024, 0, stream>>>(probs16, dgp, ellp,
                                                       ovf_cnt, ovf_pairs, out);
}

// Round 12
// 145.269 us; speedup vs baseline: 1.7637x; 1.0202x over previous
//
#include <hip/hip_runtime.h>
#include <hip/hip_bf16.h>

#define BDIM 16384
#define CDIM 128
#define FDIM 5000
#define EDIM 20000
#define ELLW 16
#define MAXOVF 20000
#define NT4  10       // n-tile QUADS: 40 n-tiles / 4

typedef __attribute__((ext_vector_type(8))) short short8;
typedef __attribute__((ext_vector_type(4))) float f32x4;
typedef __attribute__((ext_vector_type(2))) float f32x2;
typedef __attribute__((ext_vector_type(2))) int i32x2;
typedef __attribute__((ext_vector_type(8))) unsigned short upk8;
typedef __attribute__((ext_vector_type(4))) unsigned short upk4;
typedef __attribute__((ext_vector_type(2))) unsigned int u32x2;

__device__ __forceinline__ unsigned short f2bf(float f) {
    unsigned int u = __builtin_bit_cast(unsigned int, f);
    u = (u + 0x7fffu + ((u >> 16) & 1u)) >> 16;   // RNE
    return (unsigned short)u;
}
__device__ __forceinline__ float bf2f(unsigned short s) {
    unsigned int u = ((unsigned int)s) << 16;
    return __builtin_bit_cast(float, u);
}
// byte k of w -> bf16 of the integer value (EXACT for ints 0..255)
__device__ __forceinline__ unsigned short q2bf(unsigned int w, int k) {
    float f = (float)((w >> (8 * k)) & 0xFFu);    // v_cvt_f32_ubyteN
    return (unsigned short)(__builtin_bit_cast(unsigned int, f) >> 16);
}
__device__ __forceinline__ upk4 umax4(upk4 a, upk4 b) {
#if __has_builtin(__builtin_elementwise_max)
    return __builtin_elementwise_max(a, b);   // 2x v_pk_max_u16
#else
    upk4 r;
    #pragma unroll
    for (int j = 0; j < 4; ++j) r[j] = a[j] > b[j] ? a[j] : b[j];
    return r;
#endif
}
// single v_rcp_f32. VERIFIED WIN round 2: 178.96 -> 159.24 us.
__device__ __forceinline__ float fast_rcp(float x) {
#if __has_builtin(__builtin_amdgcn_rcpf)
    return __builtin_amdgcn_rcpf(x);
#else
    return 1.0f / x;
#endif
}
// async global->LDS, 16B per lane; LDS dest = firstlane base + lane*16
__device__ __forceinline__ void gll16(const unsigned short* g, unsigned short* l) {
    __builtin_amdgcn_global_load_lds(
        (const __attribute__((address_space(1))) void*)g,
        (__attribute__((address_space(3))) void*)l, 16, 0, 0);
}

// ---------------------------------------------------------------------------
// prep1: blocks [0,1024): x f32 -> bf16 (2048 elems/block)
//        blocks [1024,1181): W[k][f] -> Wt[f][k] bf16, LDS-tiled
//        blocks [1181,1201): ELL init (all 16 slots = self), cur=1, ovf=0
// ---------------------------------------------------------------------------
__global__ __launch_bounds__(256) void prep1_kernel(
    const float* __restrict__ x, const float* __restrict__ W,
    unsigned short* __restrict__ xb, unsigned short* __restrict__ wt,
    unsigned short* __restrict__ ell, int* __restrict__ cur,
    int* __restrict__ ovf_cnt)
{
    __shared__ float lt[128][33];
    int bid = blockIdx.x, tid = threadIdx.x;
    if (bid < 1024) {
        size_t base = (size_t)bid * 2048 + (size_t)tid * 8;
        const f32x4* p = (const f32x4*)(x + base);
        f32x4 v0 = p[0], v1 = p[1];
        short8 o;
        o[0] = (short)f2bf(v0[0]); o[1] = (short)f2bf(v0[1]);
        o[2] = (short)f2bf(v0[2]); o[3] = (short)f2bf(v0[3]);
        o[4] = (short)f2bf(v1[0]); o[5] = (short)f2bf(v1[1]);
        o[6] = (short)f2bf(v1[2]); o[7] = (short)f2bf(v1[3]);
        *(short8*)(xb + base) = o;
    } else if (bid < 1181) {
        int f0 = (bid - 1024) * 32;
        int f_l = tid & 31, k0 = (tid >> 5) * 16;
        #pragma unroll
        for (int i = 0; i < 16; ++i) {
            int f = f0 + f_l;
            lt[k0 + i][f_l] = (f < FDIM) ? W[(size_t)(k0 + i) * FDIM + f] : 0.f;
        }
        __syncthreads();
        int f_l2 = tid >> 3, ks = (tid & 7) * 16;
        int f = f0 + f_l2;
        if (f < FDIM) {
            short8 o0, o1;
            #pragma unroll
            for (int j = 0; j < 8; ++j) o0[j] = (short)f2bf(lt[ks + j][f_l2]);
            #pragma unroll
            for (int j = 0; j < 8; ++j) o1[j] = (short)f2bf(lt[ks + 8 + j][f_l2]);
            *(short8*)(wt + (size_t)f * 128 + ks)     = o0;
            *(short8*)(wt + (size_t)f * 128 + ks + 8) = o1;
        }
    } else {
        int p = (bid - 1181) * 256 + tid;
        if (p < FDIM) {
            upk8 s;
            #pragma unroll
            for (int j = 0; j < 8; ++j) s[j] = (unsigned short)p;
            *(upk8*)(ell + (size_t)p * ELLW)     = s;
            *(upk8*)(ell + (size_t)p * ELLW + 8) = s;
            cur[p] = 1;
        }
        if (p == FDIM) *ovf_cnt = 0;
    }
}

// ---------------------------------------------------------------------------
// prep2: scatter children into ELL slots 1.. (order irrelevant: max).
// ---------------------------------------------------------------------------
__global__ __launch_bounds__(256) void prep2_kernel(
    const int* __restrict__ epar, const int* __restrict__ echild,
    int* __restrict__ cur, unsigned short* __restrict__ ell,
    int* __restrict__ ovf_cnt, int* __restrict__ ovf_pairs)
{
    int i = blockIdx.x * 256 + threadIdx.x;
    if (i < EDIM) {
        int p = epar[i], c = echild[i];
        if (p != c) {
            int pos = atomicAdd(&cur[p], 1);
            if (pos < ELLW) {
                ell[(size_t)p * ELLW + pos] = (unsigned short)c;
            } else {
                int j = atomicAdd(ovf_cnt, 1);
                if (j < MAXOVF) { ovf_pairs[2 * j] = p; ovf_pairs[2 * j + 1] = c; }
            }
        }
    }
}

// ---------------------------------------------------------------------------
// prep3: counting-sort parents by (capped) degree -> dgp[i] = perm<<8 | dg,
// and materialize permuted ELL rows (ellp[i][16] = ell[perm[i]][16]).
// VERIFIED (r11): wave-uniform degree walk, small win.
// ---------------------------------------------------------------------------
__global__ __launch_bounds__(1024) void prep3_kernel(
    const int* __restrict__ cur, const unsigned short* __restrict__ ell,
    unsigned int* __restrict__ dgp, unsigned short* __restrict__ ellp)
{
    __shared__ int hist[32];
    __shared__ int base[32];
    int tid = threadIdx.x;
    if (tid < 32) hist[tid] = 0;
    __syncthreads();
    for (int p = tid; p < FDIM; p += 1024) {
        int d = cur[p]; if (d > 31) d = 31;
        atomicAdd(&hist[d], 1);
    }
    __syncthreads();
    if (tid == 0) {
        int acc = 0;
        for (int b = 0; b < 32; ++b) { base[b] = acc; acc += hist[b]; }
    }
    __syncthreads();
    for (int p = tid; p < FDIM; p += 1024) {
        int d = cur[p]; if (d > 31) d = 31;
        int pos = atomicAdd(&base[d], 1);
        int dcap = cur[p]; if (dcap > 255) dcap = 255;
        dgp[pos] = ((unsigned int)p << 8) | (unsigned int)dcap;
    }
    __syncthreads();   // dgp visible block-wide
    for (int i = tid; i < FDIM; i += 1024) {
        int pr = (int)(dgp[i] >> 8);
        upk8 lo = *(const upk8*)(ell + (size_t)pr * ELLW);
        upk8 hi = *(const upk8*)(ell + (size_t)pr * ELLW + 8);
        *(upk8*)(ellp + (size_t)i * ELLW)     = lo;
        *(upk8*)(ellp + (size_t)i * ELLW + 8) = hi;
    }
}

// ---------------------------------------------------------------------------
// gemm8u: r10/r11-verified structure; epilogue computes sigmoid (rcp form,
// r2-verified) + u8 quant and stores ONE u32 (4 batch vals) to the
// half-slab u8 layout [slab*2+(g&1)][FDIM][4]. Halves probs traffic
// 164 -> 82 MB (the r4 u16-key detour paid 164 MB of HBM for a VALU win;
// u8 sigmoid-quant IS the optimal monotone 8-bit code, absmax 0.0059
// passed r0-r2).
// ---------------------------------------------------------------------------
__global__ __launch_bounds__(512, 4) void gemm8u_kernel(
    const unsigned short* __restrict__ xb,   // [BDIM][128] bf16
    const unsigned short* __restrict__ wt,   // [FDIM][128] bf16
    const float* __restrict__ bias,
    unsigned char* __restrict__ probs8)      // [BDIM/8*2][FDIM][4] u8
{
    __shared__ unsigned short lA[128 * 128];
    __shared__ unsigned short lB[128 * 128];

    int bid0 = blockIdx.x;
    int bid  = (bid0 & 7) * (128 * NT4 / 8) + (bid0 >> 3);   // XCD swizzle
    int bm = bid / NT4, bq = bid % NT4;
    int tid = threadIdx.x;
    int lane = tid & 63, w = tid >> 6;       // 8 waves
    int wm = w >> 2, wn = w & 3;
    int g = lane >> 4, lr = lane & 15;
    int lrow = lane >> 4;                    // row within 4-row chunk
    int lcol = (lane & 15) << 4;             // byte col

    auto stageA = [&]() {
        #pragma unroll
        for (int it = 0; it < 4; ++it) {
            int ci = w * 4 + it;             // chunk 0..31
            int row = ci * 4 + lrow;
            int sw = lcol ^ ((row & 7) << 4);
            gll16(xb + ((size_t)(bm * 128 + row) << 7) + (sw >> 1),
                  lA + ci * 512);
        }
    };
    auto stageB = [&](int bn) {
        #pragma unroll
        for (int it = 0; it < 4; ++it) {
            int ci = w * 4 + it;
            int row = ci * 4 + lrow;
            int sw = lcol ^ ((row & 7) << 4);
            gll16(wt + ((size_t)(bn * 128 + row) << 7) + (sw >> 1),
                  lB + ci * 512);
        }
    };
    auto compute = [&](f32x4 (&acc)[4][2]) {
        #pragma unroll
        for (int ks = 0; ks < 4; ++ks) {
            int cbk = ks * 64 + g * 16;
            short8 af[4], bf[2];
            #pragma unroll
            for (int mi = 0; mi < 4; ++mi) {
                int row = wm * 64 + mi * 16 + lr;
                af[mi] = *(const short8*)((const char*)lA + row * 256 + (cbk ^ ((row & 7) << 4)));
            }
            #pragma unroll
            for (int nj = 0; nj < 2; ++nj) {
                int row = wn * 32 + nj * 16 + lr;
                bf[nj] = *(const short8*)((const char*)lB + row * 256 + (cbk ^ ((row & 7) << 4)));
            }
            #pragma unroll
            for (int mi = 0; mi < 4; ++mi)
                #pragma unroll
                for (int nj = 0; nj < 2; ++nj)
                    acc[mi][nj] = __builtin_amdgcn_mfma_f32_16x16x32_bf16(
                        af[mi], bf[nj], acc[mi][nj], 0, 0, 0);
        }
    };
    auto epilogue = [&](int bn, f32x4 (&acc)[4][2]) {
        #pragma unroll
        for (int nj = 0; nj < 2; ++nj) {
            int f = bn * 128 + wn * 32 + nj * 16 + lr;
            bool ok = (f < FDIM);
            float bb = ok ? bias[f] : 0.f;
            #pragma unroll
            for (int mi = 0; mi < 4; ++mi) {
                unsigned int pk = 0;
                #pragma unroll
                for (int j = 0; j < 4; ++j) {
                    float z = acc[mi][nj][j] + bb;
                    float pr = fast_rcp(1.0f + __expf(-z));   // v_rcp_f32
                    unsigned int q = (unsigned int)(pr * 255.f + 0.5f);
                    pk |= q << (8 * j);
                }
                if (ok) {
                    int slab = bm * 16 + wm * 8 + mi * 2 + (g >> 1);
                    int grp  = slab * 2 + (g & 1);   // half-slab group
                    *(unsigned int*)(probs8 + ((size_t)grp * FDIM + f) * 4) = pk;
                }
            }
        }
    };

    stageA();
    stageB(bq * 4);
    __syncthreads();                     // drains vmcnt -> tiles resident

    f32x4 zero = {0.f, 0.f, 0.f, 0.f};
    for (int t = 0; t < 4; ++t) {
        f32x4 acc[4][2];
        #pragma unroll
        for (int mi = 0; mi < 4; ++mi) { acc[mi][0] = zero; acc[mi][1] = zero; }
        compute(acc);
        if (t < 3) {
            __syncthreads();             // all waves done reading lB(t)
            stageB(bq * 4 + t + 1);      // async B(t+1), hides under epilogue
            epilogue(bq * 4 + t, acc);
            __syncthreads();             // drains vmcnt -> lB(t+1) ready
        } else {
            epilogue(bq * 4 + t, acc);
        }
    }
}

// ---------------------------------------------------------------------------
// segmax18: r11-verified gather structure (half-slab, b64 rows, degree-
// sorted via dgp/ellp, LDS xchg) with: (a) staging reads the u8 probs
// (82 MB not 164) and converts to the bf16-int u16 table (r0's proven
// q2bf path); (b) final store is bf2f * (1/255) -- sigmoid left the seg
// store path (it's in gemm now). Gather loop byte-identical to r11.
// ---------------------------------------------------------------------------
__global__ __launch_bounds__(1024) void segmax18_kernel(
    const unsigned char* __restrict__ probs8,    // [4096][FDIM][4] u8
    const unsigned int* __restrict__ dgp,        // [FDIM] perm<<8|dg (sorted)
    const unsigned short* __restrict__ ellp,     // [FDIM][16] permuted ELL
    const int* __restrict__ ovf_cnt, const int* __restrict__ ovf_pairs,
    float* __restrict__ out)
{
    __shared__ unsigned short l[FDIM * 4];       // 40000 B table (bf16 of q)
    __shared__ unsigned short xchg[FDIM * 4];    // 40000 B maxkey exchange
    int grp = blockIdx.x;                        // half-slab group
    int b0 = (grp >> 1) * 8 + (grp & 1) * 4;     // first of 4 batch rows
    int tid = threadIdx.x;
    const unsigned char* src = probs8 + (size_t)grp * FDIM * 4;

    for (int c = tid; c < FDIM; c += 1024) {
        unsigned int v = *(const unsigned int*)(src + (size_t)c * 4);
        upk4 o;
        #pragma unroll
        for (int k = 0; k < 4; ++k) o[k] = q2bf(v, k);
        *(upk4*)(l + (size_t)c * 4) = o;
    }
    __syncthreads();                             // table resident

    int novf = *ovf_cnt; if (novf > MAXOVF) novf = MAXOVF;

    // ---- gather phase: sorted order, 2 slots/thread/iter (r11-identical) ----
    for (int w0 = tid * 2; w0 < FDIM; w0 += 2048) {
        int w1 = w0 + 1;
        u32x2 dv = *(const u32x2*)(dgp + w0);
        int pa = (int)(dv[0] >> 8), da = (int)(dv[0] & 255u);
        int pb = (int)(dv[1] >> 8), db = (int)(dv[1] & 255u);
        upk8 ea = *(const upk8*)(ellp + (size_t)w0 * ELLW);   // slots 0-7
        upk8 eb = *(const upk8*)(ellp + (size_t)w1 * ELLW);
        upk4 ma = *(const upk4*)(l + (size_t)ea[0] * 4);
        upk4 mb = *(const upk4*)(l + (size_t)eb[0] * 4);
        ma = umax4(ma, *(const upk4*)(l + (size_t)ea[1] * 4));
        mb = umax4(mb, *(const upk4*)(l + (size_t)eb[1] * 4));
        ma = umax4(ma, *(const upk4*)(l + (size_t)ea[2] * 4));
        mb = umax4(mb, *(const upk4*)(l + (size_t)eb[2] * 4));
        ma = umax4(ma, *(const upk4*)(l + (size_t)ea[3] * 4));
        mb = umax4(mb, *(const upk4*)(l + (size_t)eb[3] * 4));
        if (da > 4) {
            ma = umax4(ma, *(const upk4*)(l + (size_t)ea[4] * 4));
            ma = umax4(ma, *(const upk4*)(l + (size_t)ea[5] * 4));
            ma = umax4(ma, *(const upk4*)(l + (size_t)ea[6] * 4));
            ma = umax4(ma, *(const upk4*)(l + (size_t)ea[7] * 4));
        }
        if (db > 4) {
            mb = umax4(mb, *(const upk4*)(l + (size_t)eb[4] * 4));
            mb = umax4(mb, *(const upk4*)(l + (size_t)eb[5] * 4));
            mb = umax4(mb, *(const upk4*)(l + (size_t)eb[6] * 4));
            mb = umax4(mb, *(const upk4*)(l + (size_t)eb[7] * 4));
        }
        if (da > 8) {
            upk8 e = *(const upk8*)(ellp + (size_t)w0 * ELLW + 8);
            #pragma unroll
            for (int k = 0; k < 8; ++k)
                ma = umax4(ma, *(const upk4*)(l + (size_t)e[k] * 4));
        }
        if (db > 8) {
            upk8 e = *(const upk8*)(ellp + (size_t)w1 * ELLW + 8);
            #pragma unroll
            for (int k = 0; k < 8; ++k)
                mb = umax4(mb, *(const upk4*)(l + (size_t)e[k] * 4));
        }
        if (da > ELLW) {
            for (int i = 0; i < novf; ++i)
                if (ovf_pairs[2 * i] == pa)
                    ma = umax4(ma, *(const upk4*)(l + (size_t)ovf_pairs[2 * i + 1] * 4));
        }
        if (db > ELLW) {
            for (int i = 0; i < novf; ++i)
                if (ovf_pairs[2 * i] == pb)
                    mb = umax4(mb, *(const upk4*)(l + (size_t)ovf_pairs[2 * i + 1] * 4));
        }
        *(upk4*)(xchg + (size_t)pa * 4) = ma;
        *(upk4*)(xchg + (size_t)pb * 4) = mb;
    }
    __syncthreads();                             // xchg complete

    // ---- canonical phase: 4 adjacent parents/thread, f32x4 stores ----
    for (int p0 = tid * 4; p0 < FDIM; p0 += 4096) {   // 5000%4==0
        upk4 m0 = *(const upk4*)(xchg + (size_t)p0 * 4);
        upk4 m1 = *(const upk4*)(xchg + (size_t)(p0 + 1) * 4);
        upk4 m2 = *(const upk4*)(xchg + (size_t)(p0 + 2) * 4);
        upk4 m3 = *(const upk4*)(xchg + (size_t)(p0 + 3) * 4);
        size_t o = (size_t)b0 * FDIM + p0;
        #pragma unroll
        for (int r = 0; r < 4; ++r) {
            f32x4 v4;
            v4[0] = bf2f(m0[r]) * (1.f / 255.f);
            v4[1] = bf2f(m1[r]) * (1.f / 255.f);
            v4[2] = bf2f(m2[r]) * (1.f / 255.f);
            v4[3] = bf2f(m3[r]) * (1.f / 255.f);
            __builtin_nontemporal_store(v4, (f32x4*)(out + o + (size_t)r * FDIM));
        }
    }
}

// ---------------------------------------------------------------------------
extern "C" void kernel_launch(void* const* d_in, const int* in_sizes, int n_in,
                              void* d_out, int out_size, void* d_ws, size_t ws_size,
                              hipStream_t stream)
{
    const float* x     = (const float*)d_in[0];
    const float* W     = (const float*)d_in[1];
    const float* bias  = (const float*)d_in[2];
    const int*   epar  = (const int*)d_in[3];
    const int*   echild= (const int*)d_in[4];
    float* out = (float*)d_out;

    char* ws = (char*)d_ws;
    size_t off = 0;
    auto alloc = [&](size_t bytes) { size_t o = off; off = (off + bytes + 255) & ~(size_t)255; return o; };
    size_t o_probs  = alloc((size_t)BDIM * FDIM);        // u8 (half-slab layout)
    size_t o_xb     = alloc((size_t)BDIM * CDIM * 2);
    size_t o_wt     = alloc((size_t)FDIM * CDIM * 2);
    size_t o_ell    = alloc((size_t)FDIM * ELLW * 2);
    size_t o_cur    = alloc((size_t)FDIM * 4);
    size_t o_ovfc   = alloc(4);
    size_t o_ovfp   = alloc((size_t)MAXOVF * 8);
    size_t o_dgp    = alloc((size_t)FDIM * 4);
    size_t o_ellp   = alloc((size_t)FDIM * ELLW * 2);
    (void)ws_size; (void)in_sizes; (void)n_in; (void)out_size;

    unsigned char*  probs8 = (unsigned char*)(ws + o_probs);
    unsigned short* xb     = (unsigned short*)(ws + o_xb);
    unsigned short* wt     = (unsigned short*)(ws + o_wt);
    unsigned short* ell    = (unsigned short*)(ws + o_ell);
    int* cur      = (int*)(ws + o_cur);
    int* ovf_cnt  = (int*)(ws + o_ovfc);
    int* ovf_pairs= (int*)(ws + o_ovfp);
    unsigned int*   dgp  = (unsigned int*)(ws + o_dgp);
    unsigned short* ellp = (unsigned short*)(ws + o_ellp);

    prep1_kernel<<<1201, 256, 0, stream>>>(x, W, xb, wt, ell, cur, ovf_cnt);
    prep2_kernel<<<79, 256, 0, stream>>>(epar, echild, cur, ell, ovf_cnt, ovf_pairs);
    prep3_kernel<<<1, 1024, 0, stream>>>(cur, ell, dgp, ellp);
    gemm8u_kernel<<<128 * NT4, 512, 0, stream>>>(xb, wt, bias, probs8);
    segmax18_kernel<<<BDIM / 8 * 2, 1024, 0, stream>>>(probs8, dgp, ellp,
                                                       ovf_cnt, ovf_pairs, out);
}

// Round 13
// 143.294 us; speedup vs baseline: 1.7880x; 1.0138x over previous
//
#include <hip/hip_runtime.h>
#include <hip/hip_bf16.h>

#define BDIM 16384
#define CDIM 128
#define FDIM 5000
#define EDIM 20000
#define ELLW 16
#define MAXOVF 20000
#define NT4  10       // n-tile QUADS: 40 n-tiles / 4

typedef __attribute__((ext_vector_type(8))) short short8;
typedef __attribute__((ext_vector_type(4))) float f32x4;
typedef __attribute__((ext_vector_type(2))) float f32x2;
typedef __attribute__((ext_vector_type(2))) int i32x2;
typedef __attribute__((ext_vector_type(8))) unsigned short upk8;
typedef __attribute__((ext_vector_type(4))) unsigned short upk4;
typedef __attribute__((ext_vector_type(2))) unsigned short upk2;
typedef __attribute__((ext_vector_type(2))) unsigned int u32x2;
typedef __attribute__((ext_vector_type(4))) unsigned int u32x4;

__device__ __forceinline__ unsigned short f2bf(float f) {
    unsigned int u = __builtin_bit_cast(unsigned int, f);
    u = (u + 0x7fffu + ((u >> 16) & 1u)) >> 16;   // RNE
    return (unsigned short)u;
}
// packed max of two u16 pairs (v_pk_max_u16)
__device__ __forceinline__ unsigned int pkmax2(unsigned int a, unsigned int b) {
#if __has_builtin(__builtin_elementwise_max)
    upk2 r = __builtin_elementwise_max(__builtin_bit_cast(upk2, a),
                                       __builtin_bit_cast(upk2, b));
    return __builtin_bit_cast(unsigned int, r);
#else
    unsigned int lo = ((a & 0xFFFFu) > (b & 0xFFFFu)) ? (a & 0xFFFFu) : (b & 0xFFFFu);
    unsigned int hi = ((a >> 16) > (b >> 16)) ? (a & 0xFFFF0000u) : (b & 0xFFFF0000u);
    return lo | hi;
#endif
}
// zero-extend bytes {0,1} / {2,3} of v into two u16 lanes (v_perm_b32, 0x0C=zero)
__device__ __forceinline__ unsigned int lo16x2(unsigned int v) {
#if __has_builtin(__builtin_amdgcn_perm)
    return __builtin_amdgcn_perm(0u, v, 0x0C010C00u);
#else
    return (v & 0xFFu) | ((v << 8) & 0x00FF0000u);
#endif
}
__device__ __forceinline__ unsigned int hi16x2(unsigned int v) {
#if __has_builtin(__builtin_amdgcn_perm)
    return __builtin_amdgcn_perm(0u, v, 0x0C030C02u);
#else
    return ((v >> 16) & 0xFFu) | ((v >> 8) & 0x00FF0000u);
#endif
}
// single v_rcp_f32. VERIFIED WIN round 2: 178.96 -> 159.24 us.
__device__ __forceinline__ float fast_rcp(float x) {
#if __has_builtin(__builtin_amdgcn_rcpf)
    return __builtin_amdgcn_rcpf(x);
#else
    return 1.0f / x;
#endif
}
// async global->LDS, 16B per lane; LDS dest = firstlane base + lane*16
__device__ __forceinline__ void gll16(const unsigned short* g, unsigned short* l) {
    __builtin_amdgcn_global_load_lds(
        (const __attribute__((address_space(1))) void*)g,
        (__attribute__((address_space(3))) void*)l, 16, 0, 0);
}

// ---------------------------------------------------------------------------
// prep1: blocks [0,1024): x f32 -> bf16 (2048 elems/block)
//        blocks [1024,1181): W[k][f] -> Wt[f][k] bf16, LDS-tiled
//        blocks [1181,1201): ELL init (all 16 slots = self), cur=1, ovf=0
// ---------------------------------------------------------------------------
__global__ __launch_bounds__(256) void prep1_kernel(
    const float* __restrict__ x, const float* __restrict__ W,
    unsigned short* __restrict__ xb, unsigned short* __restrict__ wt,
    unsigned short* __restrict__ ell, int* __restrict__ cur,
    int* __restrict__ ovf_cnt)
{
    __shared__ float lt[128][33];
    int bid = blockIdx.x, tid = threadIdx.x;
    if (bid < 1024) {
        size_t base = (size_t)bid * 2048 + (size_t)tid * 8;
        const f32x4* p = (const f32x4*)(x + base);
        f32x4 v0 = p[0], v1 = p[1];
        short8 o;
        o[0] = (short)f2bf(v0[0]); o[1] = (short)f2bf(v0[1]);
        o[2] = (short)f2bf(v0[2]); o[3] = (short)f2bf(v0[3]);
        o[4] = (short)f2bf(v1[0]); o[5] = (short)f2bf(v1[1]);
        o[6] = (short)f2bf(v1[2]); o[7] = (short)f2bf(v1[3]);
        *(short8*)(xb + base) = o;
    } else if (bid < 1181) {
        int f0 = (bid - 1024) * 32;
        int f_l = tid & 31, k0 = (tid >> 5) * 16;
        #pragma unroll
        for (int i = 0; i < 16; ++i) {
            int f = f0 + f_l;
            lt[k0 + i][f_l] = (f < FDIM) ? W[(size_t)(k0 + i) * FDIM + f] : 0.f;
        }
        __syncthreads();
        int f_l2 = tid >> 3, ks = (tid & 7) * 16;
        int f = f0 + f_l2;
        if (f < FDIM) {
            short8 o0, o1;
            #pragma unroll
            for (int j = 0; j < 8; ++j) o0[j] = (short)f2bf(lt[ks + j][f_l2]);
            #pragma unroll
            for (int j = 0; j < 8; ++j) o1[j] = (short)f2bf(lt[ks + 8 + j][f_l2]);
            *(short8*)(wt + (size_t)f * 128 + ks)     = o0;
            *(short8*)(wt + (size_t)f * 128 + ks + 8) = o1;
        }
    } else {
        int p = (bid - 1181) * 256 + tid;
        if (p < FDIM) {
            upk8 s;
            #pragma unroll
            for (int j = 0; j < 8; ++j) s[j] = (unsigned short)p;
            *(upk8*)(ell + (size_t)p * ELLW)     = s;
            *(upk8*)(ell + (size_t)p * ELLW + 8) = s;
            cur[p] = 1;
        }
        if (p == FDIM) *ovf_cnt = 0;
    }
}

// ---------------------------------------------------------------------------
// prep2: scatter children into ELL slots 1.. (order irrelevant: max).
// ---------------------------------------------------------------------------
__global__ __launch_bounds__(256) void prep2_kernel(
    const int* __restrict__ epar, const int* __restrict__ echild,
    int* __restrict__ cur, unsigned short* __restrict__ ell,
    int* __restrict__ ovf_cnt, int* __restrict__ ovf_pairs)
{
    int i = blockIdx.x * 256 + threadIdx.x;
    if (i < EDIM) {
        int p = epar[i], c = echild[i];
        if (p != c) {
            int pos = atomicAdd(&cur[p], 1);
            if (pos < ELLW) {
                ell[(size_t)p * ELLW + pos] = (unsigned short)c;
            } else {
                int j = atomicAdd(ovf_cnt, 1);
                if (j < MAXOVF) { ovf_pairs[2 * j] = p; ovf_pairs[2 * j + 1] = c; }
            }
        }
    }
}

// ---------------------------------------------------------------------------
// prep3: counting-sort parents by (capped) degree -> dgp[i] = perm<<8 | dg,
// and materialize permuted ELL rows. VERIFIED (r11).
// ---------------------------------------------------------------------------
__global__ __launch_bounds__(1024) void prep3_kernel(
    const int* __restrict__ cur, const unsigned short* __restrict__ ell,
    unsigned int* __restrict__ dgp, unsigned short* __restrict__ ellp)
{
    __shared__ int hist[32];
    __shared__ int base[32];
    int tid = threadIdx.x;
    if (tid < 32) hist[tid] = 0;
    __syncthreads();
    for (int p = tid; p < FDIM; p += 1024) {
        int d = cur[p]; if (d > 31) d = 31;
        atomicAdd(&hist[d], 1);
    }
    __syncthreads();
    if (tid == 0) {
        int acc = 0;
        for (int b = 0; b < 32; ++b) { base[b] = acc; acc += hist[b]; }
    }
    __syncthreads();
    for (int p = tid; p < FDIM; p += 1024) {
        int d = cur[p]; if (d > 31) d = 31;
        int pos = atomicAdd(&base[d], 1);
        int dcap = cur[p]; if (dcap > 255) dcap = 255;
        dgp[pos] = ((unsigned int)p << 8) | (unsigned int)dcap;
    }
    __syncthreads();   // dgp visible block-wide
    for (int i = tid; i < FDIM; i += 1024) {
        int pr = (int)(dgp[i] >> 8);
        upk8 lo = *(const upk8*)(ell + (size_t)pr * ELLW);
        upk8 hi = *(const upk8*)(ell + (size_t)pr * ELLW + 8);
        *(upk8*)(ellp + (size_t)i * ELLW)     = lo;
        *(upk8*)(ellp + (size_t)i * ELLW + 8) = hi;
    }
}

// ---------------------------------------------------------------------------
// gemm8u: EXACT r12-verified version (145.27 us pipeline). u8 sigmoid-quant
// epilogue, half-slab layout [slab*2+(g&1)][FDIM][4].
// ---------------------------------------------------------------------------
__global__ __launch_bounds__(512, 4) void gemm8u_kernel(
    const unsigned short* __restrict__ xb,   // [BDIM][128] bf16
    const unsigned short* __restrict__ wt,   // [FDIM][128] bf16
    const float* __restrict__ bias,
    unsigned char* __restrict__ probs8)      // [BDIM/8*2][FDIM][4] u8
{
    __shared__ unsigned short lA[128 * 128];
    __shared__ unsigned short lB[128 * 128];

    int bid0 = blockIdx.x;
    int bid  = (bid0 & 7) * (128 * NT4 / 8) + (bid0 >> 3);   // XCD swizzle
    int bm = bid / NT4, bq = bid % NT4;
    int tid = threadIdx.x;
    int lane = tid & 63, w = tid >> 6;       // 8 waves
    int wm = w >> 2, wn = w & 3;
    int g = lane >> 4, lr = lane & 15;
    int lrow = lane >> 4;                    // row within 4-row chunk
    int lcol = (lane & 15) << 4;             // byte col

    auto stageA = [&]() {
        #pragma unroll
        for (int it = 0; it < 4; ++it) {
            int ci = w * 4 + it;             // chunk 0..31
            int row = ci * 4 + lrow;
            int sw = lcol ^ ((row & 7) << 4);
            gll16(xb + ((size_t)(bm * 128 + row) << 7) + (sw >> 1),
                  lA + ci * 512);
        }
    };
    auto stageB = [&](int bn) {
        #pragma unroll
        for (int it = 0; it < 4; ++it) {
            int ci = w * 4 + it;
            int row = ci * 4 + lrow;
            int sw = lcol ^ ((row & 7) << 4);
            gll16(wt + ((size_t)(bn * 128 + row) << 7) + (sw >> 1),
                  lB + ci * 512);
        }
    };
    auto compute = [&](f32x4 (&acc)[4][2]) {
        #pragma unroll
        for (int ks = 0; ks < 4; ++ks) {
            int cbk = ks * 64 + g * 16;
            short8 af[4], bf[2];
            #pragma unroll
            for (int mi = 0; mi < 4; ++mi) {
                int row = wm * 64 + mi * 16 + lr;
                af[mi] = *(const short8*)((const char*)lA + row * 256 + (cbk ^ ((row & 7) << 4)));
            }
            #pragma unroll
            for (int nj = 0; nj < 2; ++nj) {
                int row = wn * 32 + nj * 16 + lr;
                bf[nj] = *(const short8*)((const char*)lB + row * 256 + (cbk ^ ((row & 7) << 4)));
            }
            #pragma unroll
            for (int mi = 0; mi < 4; ++mi)
                #pragma unroll
                for (int nj = 0; nj < 2; ++nj)
                    acc[mi][nj] = __builtin_amdgcn_mfma_f32_16x16x32_bf16(
                        af[mi], bf[nj], acc[mi][nj], 0, 0, 0);
        }
    };
    auto epilogue = [&](int bn, f32x4 (&acc)[4][2]) {
        #pragma unroll
        for (int nj = 0; nj < 2; ++nj) {
            int f = bn * 128 + wn * 32 + nj * 16 + lr;
            bool ok = (f < FDIM);
            float bb = ok ? bias[f] : 0.f;
            #pragma unroll
            for (int mi = 0; mi < 4; ++mi) {
                unsigned int pk = 0;
                #pragma unroll
                for (int j = 0; j < 4; ++j) {
                    float z = acc[mi][nj][j] + bb;
                    float pr = fast_rcp(1.0f + __expf(-z));   // v_rcp_f32
                    unsigned int q = (unsigned int)(pr * 255.f + 0.5f);
                    pk |= q << (8 * j);
                }
                if (ok) {
                    int slab = bm * 16 + wm * 8 + mi * 2 + (g >> 1);
                    int grp  = slab * 2 + (g & 1);   // half-slab group
                    *(unsigned int*)(probs8 + ((size_t)grp * FDIM + f) * 4) = pk;
                }
            }
        }
    };

    stageA();
    stageB(bq * 4);
    __syncthreads();                     // drains vmcnt -> tiles resident

    f32x4 zero = {0.f, 0.f, 0.f, 0.f};
    for (int t = 0; t < 4; ++t) {
        f32x4 acc[4][2];
        #pragma unroll
        for (int mi = 0; mi < 4; ++mi) { acc[mi][0] = zero; acc[mi][1] = zero; }
        compute(acc);
        if (t < 3) {
            __syncthreads();             // all waves done reading lB(t)
            stageB(bq * 4 + t + 1);      // async B(t+1), hides under epilogue
            epilogue(bq * 4 + t, acc);
            __syncthreads();             // drains vmcnt -> lB(t+1) ready
        } else {
            epilogue(bq * 4 + t, acc);
        }
    }
}

// ---------------------------------------------------------------------------
// segmax19: table is RAW u8 (20KB, gll16-staged with ZERO conversion VALU).
// A term's whole row = 4B = one dword -> gathers are ds_read_b32 (1 bank/
// lane, random rows ~2-way = free, m136) vs the 8B/1.58x of r12. Max runs
// in u16-pair accumulators: per gather 2x v_perm_b32 zero-extend + 2x
// v_pk_max_u16 (VALU, rides under LDS). xchg split into xlo/xhi u32 maps.
// Canonical phase extracts u16 -> cvt -> *(1/255) -> f32x4 stores.
// Gather structure (sorted order, ell walk) identical to r11/r12.
// LDS: 20000+20000+20000 = 60000B -> 2 blocks/CU.
// ---------------------------------------------------------------------------
__global__ __launch_bounds__(1024) void segmax19_kernel(
    const unsigned char* __restrict__ probs8,    // [4096][FDIM][4] u8
    const unsigned int* __restrict__ dgp,        // [FDIM] perm<<8|dg (sorted)
    const unsigned short* __restrict__ ellp,     // [FDIM][16] permuted ELL
    const int* __restrict__ ovf_cnt, const int* __restrict__ ovf_pairs,
    float* __restrict__ out)
{
    __shared__ unsigned int l32[FDIM];           // 20000 B raw u8 rows
    __shared__ unsigned int xlo[FDIM];           // 20000 B acc lo (rows 0,1)
    __shared__ unsigned int xhi[FDIM];           // 20000 B acc hi (rows 2,3)
    int grp = blockIdx.x;                        // half-slab group
    int b0 = (grp >> 1) * 8 + (grp & 1) * 4;     // first of 4 batch rows
    int tid = threadIdx.x;
    const unsigned short* src =
        (const unsigned short*)(probs8 + (size_t)grp * FDIM * 4);

    for (int c = tid; c < FDIM / 4; c += 1024) { // 1250 x 16B chunks
        gll16(src + (size_t)c * 8, (unsigned short*)l32 + (size_t)c * 8);
    }
    __syncthreads();                             // table resident

    int novf = *ovf_cnt; if (novf > MAXOVF) novf = MAXOVF;

    // ---- gather phase: sorted order, 2 parents/thread/iter ----
    for (int w0 = tid * 2; w0 < FDIM; w0 += 2048) {
        int w1 = w0 + 1;
        u32x2 dv = *(const u32x2*)(dgp + w0);
        int pa = (int)(dv[0] >> 8), da = (int)(dv[0] & 255u);
        int pb = (int)(dv[1] >> 8), db = (int)(dv[1] & 255u);
        upk8 ea = *(const upk8*)(ellp + (size_t)w0 * ELLW);   // slots 0-7
        upk8 eb = *(const upk8*)(ellp + (size_t)w1 * ELLW);
        unsigned int va = l32[ea[0]], vb = l32[eb[0]];
        unsigned int alo = lo16x2(va), ahi = hi16x2(va);
        unsigned int blo = lo16x2(vb), bhi = hi16x2(vb);
        #pragma unroll
        for (int s = 1; s < 4; ++s) {
            unsigned int u = l32[ea[s]], v = l32[eb[s]];
            alo = pkmax2(alo, lo16x2(u)); ahi = pkmax2(ahi, hi16x2(u));
            blo = pkmax2(blo, lo16x2(v)); bhi = pkmax2(bhi, hi16x2(v));
        }
        if (da > 4) {
            #pragma unroll
            for (int s = 4; s < 8; ++s) {
                unsigned int u = l32[ea[s]];
                alo = pkmax2(alo, lo16x2(u)); ahi = pkmax2(ahi, hi16x2(u));
            }
        }
        if (db > 4) {
            #pragma unroll
            for (int s = 4; s < 8; ++s) {
                unsigned int v = l32[eb[s]];
                blo = pkmax2(blo, lo16x2(v)); bhi = pkmax2(bhi, hi16x2(v));
            }
        }
        if (da > 8) {
            upk8 e = *(const upk8*)(ellp + (size_t)w0 * ELLW + 8);
            #pragma unroll
            for (int k = 0; k < 8; ++k) {
                unsigned int u = l32[e[k]];
                alo = pkmax2(alo, lo16x2(u)); ahi = pkmax2(ahi, hi16x2(u));
            }
        }
        if (db > 8) {
            upk8 e = *(const upk8*)(ellp + (size_t)w1 * ELLW + 8);
            #pragma unroll
            for (int k = 0; k < 8; ++k) {
                unsigned int v = l32[e[k]];
                blo = pkmax2(blo, lo16x2(v)); bhi = pkmax2(bhi, hi16x2(v));
            }
        }
        if (da > ELLW) {
            for (int i = 0; i < novf; ++i)
                if (ovf_pairs[2 * i] == pa) {
                    unsigned int u = l32[ovf_pairs[2 * i + 1]];
                    alo = pkmax2(alo, lo16x2(u)); ahi = pkmax2(ahi, hi16x2(u));
                }
        }
        if (db > ELLW) {
            for (int i = 0; i < novf; ++i)
                if (ovf_pairs[2 * i] == pb) {
                    unsigned int v = l32[ovf_pairs[2 * i + 1]];
                    blo = pkmax2(blo, lo16x2(v)); bhi = pkmax2(bhi, hi16x2(v));
                }
        }
        xlo[pa] = alo; xhi[pa] = ahi;
        xlo[pb] = blo; xhi[pb] = bhi;
    }
    __syncthreads();                             // exchange complete

    // ---- canonical phase: 4 adjacent parents/thread, f32x4 stores ----
    for (int p0 = tid * 4; p0 < FDIM; p0 += 4096) {   // 5000%4==0
        u32x4 lo4 = *(const u32x4*)(xlo + p0);
        u32x4 hi4 = *(const u32x4*)(xhi + p0);
        size_t o = (size_t)b0 * FDIM + p0;
        #pragma unroll
        for (int r = 0; r < 4; ++r) {
            f32x4 v4;
            #pragma unroll
            for (int j = 0; j < 4; ++j) {
                unsigned int w = (r < 2) ? lo4[j] : hi4[j];
                unsigned int q = (w >> (16 * (r & 1))) & 0xFFFFu;
                v4[j] = (float)q * (1.f / 255.f);
            }
            __builtin_nontemporal_store(v4, (f32x4*)(out + o + (size_t)r * FDIM));
        }
    }
}

// ---------------------------------------------------------------------------
extern "C" void kernel_launch(void* const* d_in, const int* in_sizes, int n_in,
                              void* d_out, int out_size, void* d_ws, size_t ws_size,
                              hipStream_t stream)
{
    const float* x     = (const float*)d_in[0];
    const float* W     = (const float*)d_in[1];
    const float* bias  = (const float*)d_in[2];
    const int*   epar  = (const int*)d_in[3];
    const int*   echild= (const int*)d_in[4];
    float* out = (float*)d_out;

    char* ws = (char*)d_ws;
    size_t off = 0;
    auto alloc = [&](size_t bytes) { size_t o = off; off = (off + bytes + 255) & ~(size_t)255; return o; };
    size_t o_probs  = alloc((size_t)BDIM * FDIM);        // u8 (half-slab layout)
    size_t o_xb     = alloc((size_t)BDIM * CDIM * 2);
    size_t o_wt     = alloc((size_t)FDIM * CDIM * 2);
    size_t o_ell    = alloc((size_t)FDIM * ELLW * 2);
    size_t o_cur    = alloc((size_t)FDIM * 4);
    size_t o_ovfc   = alloc(4);
    size_t o_ovfp   = alloc((size_t)MAXOVF * 8);
    size_t o_dgp    = alloc((size_t)FDIM * 4);
    size_t o_ellp   = alloc((size_t)FDIM * ELLW * 2);
    (void)ws_size; (void)in_sizes; (void)n_in; (void)out_size;

    unsigned char*  probs8 = (unsigned char*)(ws + o_probs);
    unsigned short* xb     = (unsigned short*)(ws + o_xb);
    unsigned short* wt     = (unsigned short*)(ws + o_wt);
    unsigned short* ell    = (unsigned short*)(ws + o_ell);
    int* cur      = (int*)(ws + o_cur);
    int* ovf_cnt  = (int*)(ws + o_ovfc);
    int* ovf_pairs= (int*)(ws + o_ovfp);
    unsigned int*   dgp  = (unsigned int*)(ws + o_dgp);
    unsigned short* ellp = (unsigned short*)(ws + o_ellp);

    prep1_kernel<<<1201, 256, 0, stream>>>(x, W, xb, wt, ell, cur, ovf_cnt);
    prep2_kernel<<<79, 256, 0, stream>>>(epar, echild, cur, ell, ovf_cnt, ovf_pairs);
    prep3_kernel<<<1, 1024, 0, stream>>>(cur, ell, dgp, ellp);
    gemm8u_kernel<<<128 * NT4, 512, 0, stream>>>(xb, wt, bias, probs8);
    segmax19_kernel<<<BDIM / 8 * 2, 1024, 0, stream>>>(probs8, dgp, ellp,
                                                       ovf_cnt, ovf_pairs, out);
}